// Round 1
// baseline (516.734 us; speedup 1.0000x reference)
//
#include <hip/hip_runtime.h>
#include <math.h>

#define NN 50000
#define NE 800000

// ---------------- CSR build ----------------

__global__ void k_zero_i32(int* __restrict__ p, int n){
  int i = blockIdx.x * blockDim.x + threadIdx.x;
  if (i < n) p[i] = 0;
}

__global__ void k_hist(const int* __restrict__ row, int* __restrict__ cnt){
  int e = blockIdx.x * blockDim.x + threadIdx.x;
  if (e < NE) atomicAdd(&cnt[row[e]], 1);
}

// single-block inclusive scan -> exclusive row_start[0..n]
__global__ __launch_bounds__(1024)
void k_scan(const int* __restrict__ cnt, int* __restrict__ start, int n){
  __shared__ int wsum[16];
  __shared__ int carry_s;
  const int t = threadIdx.x;
  if (t == 0){ carry_s = 0; start[0] = 0; }
  __syncthreads();
  for (int base = 0; base < n; base += 1024){
    int i = base + t;
    int v = (i < n) ? cnt[i] : 0;
    int lane = t & 63, w = t >> 6;
    int s = v;
    #pragma unroll
    for (int d = 1; d < 64; d <<= 1){
      int u = __shfl_up(s, d);
      if (lane >= d) s += u;
    }
    if (lane == 63) wsum[w] = s;
    __syncthreads();
    if (t == 0){
      int c = carry_s;
      #pragma unroll
      for (int k = 0; k < 16; ++k){ int x = wsum[k]; wsum[k] = c; c += x; }
      carry_s = c;
    }
    __syncthreads();
    if (i < n) start[i + 1] = s + wsum[w];
    __syncthreads();
  }
}

__global__ void k_scatter(const int* __restrict__ row, const int* __restrict__ col,
                          const float* __restrict__ val, const int* __restrict__ start,
                          int* __restrict__ cursor, int2* __restrict__ out){
  int e = blockIdx.x * blockDim.x + threadIdx.x;
  if (e >= NE) return;
  int r = row[e];
  int pos = start[r] + atomicAdd(&cursor[r], 1);
  out[pos] = make_int2(col[e], __float_as_int(val[e]));
}

// ---------------- fp32 tiled GEMM: C[M][N] = A[M][K] * B[N][K]^T ----------------
// BM=BN=128, BK=32, 256 threads, 8x8 per thread (4+4 split), k-major LDS tiles.

template<int K>
__global__ __launch_bounds__(256)
void gemm_bt(const float* __restrict__ A, const float* __restrict__ B,
             float* __restrict__ C, int M, int N){
  constexpr int BK  = 32;
  constexpr int LDT = 132;                 // padded row stride (floats) of [BK][128] tile
  constexpr int KT  = (K + BK - 1) / BK;
  __shared__ float As[BK * LDT];
  __shared__ float Bs[BK * LDT];
  const int tid = threadIdx.x;
  const int bm = blockIdx.x * 128;
  const int bn = blockIdx.y * 128;
  const int tx = tid & 15, ty = tid >> 4;
  float acc[8][8];
  #pragma unroll
  for (int i = 0; i < 8; ++i)
    #pragma unroll
    for (int j = 0; j < 8; ++j) acc[i][j] = 0.f;

  for (int kt = 0; kt < KT; ++kt){
    const int k0 = kt * BK;
    #pragma unroll
    for (int i = 0; i < 4; ++i){
      const int f  = tid + 256 * i;
      const int r  = f >> 3;          // 0..127
      const int c4 = f & 7;           // float4 index within BK
      const int gk = k0 + c4 * 4;
      // A tile
      float4 va = make_float4(0.f, 0.f, 0.f, 0.f);
      const int ga = bm + r;
      if (ga < M){
        if (gk + 3 < K){
          va = *(const float4*)(A + (size_t)ga * K + gk);
        } else {
          float tv[4] = {0.f, 0.f, 0.f, 0.f};
          #pragma unroll
          for (int e2 = 0; e2 < 4; ++e2)
            if (gk + e2 < K) tv[e2] = A[(size_t)ga * K + gk + e2];
          va = make_float4(tv[0], tv[1], tv[2], tv[3]);
        }
      }
      As[(c4 * 4 + 0) * LDT + r] = va.x;
      As[(c4 * 4 + 1) * LDT + r] = va.y;
      As[(c4 * 4 + 2) * LDT + r] = va.z;
      As[(c4 * 4 + 3) * LDT + r] = va.w;
      // B tile
      float4 vb = make_float4(0.f, 0.f, 0.f, 0.f);
      const int gb = bn + r;
      if (gb < N){
        if (gk + 3 < K){
          vb = *(const float4*)(B + (size_t)gb * K + gk);
        } else {
          float tv[4] = {0.f, 0.f, 0.f, 0.f};
          #pragma unroll
          for (int e2 = 0; e2 < 4; ++e2)
            if (gk + e2 < K) tv[e2] = B[(size_t)gb * K + gk + e2];
          vb = make_float4(tv[0], tv[1], tv[2], tv[3]);
        }
      }
      Bs[(c4 * 4 + 0) * LDT + r] = vb.x;
      Bs[(c4 * 4 + 1) * LDT + r] = vb.y;
      Bs[(c4 * 4 + 2) * LDT + r] = vb.z;
      Bs[(c4 * 4 + 3) * LDT + r] = vb.w;
    }
    __syncthreads();
    #pragma unroll
    for (int kk = 0; kk < BK; ++kk){
      const float4 a0 = *(const float4*)&As[kk * LDT + ty * 4];
      const float4 a1 = *(const float4*)&As[kk * LDT + 64 + ty * 4];
      const float4 b0 = *(const float4*)&Bs[kk * LDT + tx * 4];
      const float4 b1 = *(const float4*)&Bs[kk * LDT + 64 + tx * 4];
      const float a[8] = {a0.x, a0.y, a0.z, a0.w, a1.x, a1.y, a1.z, a1.w};
      const float b[8] = {b0.x, b0.y, b0.z, b0.w, b1.x, b1.y, b1.z, b1.w};
      #pragma unroll
      for (int i = 0; i < 8; ++i)
        #pragma unroll
        for (int j = 0; j < 8; ++j)
          acc[i][j] = fmaf(a[i], b[j], acc[i][j]);
    }
    __syncthreads();
  }
  #pragma unroll
  for (int i = 0; i < 8; ++i){
    const int r = bm + ty * 4 + (i & 3) + ((i >= 4) ? 64 : 0);
    if (r >= M) continue;
    float4 o0 = make_float4(acc[i][0], acc[i][1], acc[i][2], acc[i][3]);
    float4 o1 = make_float4(acc[i][4], acc[i][5], acc[i][6], acc[i][7]);
    *(float4*)(C + (size_t)r * N + bn + tx * 4) = o0;
    *(float4*)(C + (size_t)r * N + bn + 64 + tx * 4) = o1;
  }
}

// ---------------- SpMM (CSR, wave per row) ----------------

__global__ __launch_bounds__(256)
void spmm_bias_relu_d256(const int2* __restrict__ ecv, const int* __restrict__ start,
                         const float* __restrict__ H, const float* __restrict__ bias,
                         float* __restrict__ out){
  const int w = (blockIdx.x * 256 + threadIdx.x) >> 6;
  const int lane = threadIdx.x & 63;
  if (w >= NN) return;
  const int s = start[w], e = start[w + 1];
  float4 acc = make_float4(0.f, 0.f, 0.f, 0.f);
  for (int p = s; p < e; ++p){
    const int2 cv = ecv[p];
    const float v = __int_as_float(cv.y);
    const float4 h = *(const float4*)(H + (size_t)cv.x * 256 + lane * 4);
    acc.x = fmaf(v, h.x, acc.x);
    acc.y = fmaf(v, h.y, acc.y);
    acc.z = fmaf(v, h.z, acc.z);
    acc.w = fmaf(v, h.w, acc.w);
  }
  const float4 b = *(const float4*)(bias + lane * 4);
  acc.x = fmaxf(acc.x + b.x, 0.f);
  acc.y = fmaxf(acc.y + b.y, 0.f);
  acc.z = fmaxf(acc.z + b.z, 0.f);
  acc.w = fmaxf(acc.w + b.w, 0.f);
  *(float4*)(out + (size_t)w * 256 + lane * 4) = acc;
}

__global__ __launch_bounds__(256)
void spmm_bias_norm_d128(const int2* __restrict__ ecv, const int* __restrict__ start,
                         const float* __restrict__ H, const float* __restrict__ bias,
                         float* __restrict__ out){
  const int w = (blockIdx.x * 256 + threadIdx.x) >> 6;
  const int lane = threadIdx.x & 63;
  if (w >= NN) return;
  const int s = start[w], e = start[w + 1];
  float2 acc = make_float2(0.f, 0.f);
  for (int p = s; p < e; ++p){
    const int2 cv = ecv[p];
    const float v = __int_as_float(cv.y);
    const float2 h = *(const float2*)(H + (size_t)cv.x * 128 + lane * 2);
    acc.x = fmaf(v, h.x, acc.x);
    acc.y = fmaf(v, h.y, acc.y);
  }
  acc.x += bias[lane * 2 + 0];
  acc.y += bias[lane * 2 + 1];
  float ss = acc.x * acc.x + acc.y * acc.y;
  #pragma unroll
  for (int m = 1; m < 64; m <<= 1) ss += __shfl_xor(ss, m);
  const float inv = 1.f / fmaxf(sqrtf(ss), 1e-12f);
  float2 o = make_float2(acc.x * inv, acc.y * inv);
  *(float2*)(out + (size_t)w * 128 + lane * 2) = o;
}

// ---------------- launch ----------------

extern "C" void kernel_launch(void* const* d_in, const int* in_sizes, int n_in,
                              void* d_out, int out_size, void* d_ws, size_t ws_size,
                              hipStream_t stream){
  const float* x    = (const float*)d_in[0];
  const int*   erow = (const int*)d_in[1];
  const int*   ecol = (const int*)d_in[2];
  const float* evalv= (const float*)d_in[3];
  const float* W1   = (const float*)d_in[4];
  const float* b1   = (const float*)d_in[5];
  const float* W2   = (const float*)d_in[6];
  const float* b2   = (const float*)d_in[7];
  float* out = (float*)d_out;

  char* ws = (char*)d_ws;
  float* h1  = (float*)(ws);                    // 50000*256 f (reused as h3)
  float* h2  = (float*)(ws + 51200000);         // 50000*256 f
  int2*  ecv = (int2*)(ws + 102400000);         // 800000 int2 (col,val)
  int*   rs  = (int*)(ws + 108800000);          // 50001 row_start
  int*   cur = (int*)(ws + 109000192);          // 50000 counts/cursor
  float* h3  = h1;

  // CSR build (deterministic counts; within-row order harness-tolerance safe)
  k_zero_i32<<<196, 256, 0, stream>>>(cur, NN);
  k_hist<<<3125, 256, 0, stream>>>(erow, cur);
  k_scan<<<1, 1024, 0, stream>>>(cur, rs, NN);
  k_zero_i32<<<196, 256, 0, stream>>>(cur, NN);
  k_scatter<<<3125, 256, 0, stream>>>(erow, ecol, evalv, rs, cur, ecv);

  // layer 1: h1 = x @ W1^T ; h2 = relu(A*h1 + b1)
  gemm_bt<300><<<dim3(391, 2), 256, 0, stream>>>(x, W1, h1, NN, 256);
  spmm_bias_relu_d256<<<12500, 256, 0, stream>>>(ecv, rs, h1, b1, h2);

  // layer 2: h3 = h2 @ W2^T ; out = l2norm(A*h3 + b2)
  gemm_bt<256><<<dim3(391, 1), 256, 0, stream>>>(h2, W2, h3, NN, 128);
  spmm_bias_norm_d128<<<12500, 256, 0, stream>>>(ecv, rs, h3, b2, out);
}

// Round 2
// 423.781 us; speedup vs baseline: 1.2193x; 1.2193x over previous
//
#include <hip/hip_runtime.h>
#include <math.h>

#define NN 50000
#define NE 800000

typedef __bf16 bf16x8 __attribute__((ext_vector_type(8)));
typedef __bf16 bf16x4 __attribute__((ext_vector_type(4)));
typedef float f32x4 __attribute__((ext_vector_type(4)));

__device__ __forceinline__ void gload16(const void* g, void* l){
  __builtin_amdgcn_global_load_lds((const __attribute__((address_space(1))) void*)g,
                                   (__attribute__((address_space(3))) void*)l, 16, 0, 0);
}

// ---------------- CSR build ----------------

__global__ void k_zero_i32(int* __restrict__ p, int n){
  int i = blockIdx.x * blockDim.x + threadIdx.x;
  if (i < n) p[i] = 0;
}

__global__ void k_hist(const int* __restrict__ row, int* __restrict__ cnt){
  int e = blockIdx.x * blockDim.x + threadIdx.x;
  if (e < NE) atomicAdd(&cnt[row[e]], 1);
}

// block-local inclusive scan; rs[i+1]=local inclusive, part[b]=block total
__global__ __launch_bounds__(256)
void k_scan1(const int* __restrict__ cnt, int* __restrict__ rs, int* __restrict__ part, int n){
  const int t = threadIdx.x, b = blockIdx.x;
  const int i = b * 256 + t;
  int v = (i < n) ? cnt[i] : 0;
  const int lane = t & 63, w = t >> 6;
  int s = v;
  #pragma unroll
  for (int d = 1; d < 64; d <<= 1){ int u = __shfl_up(s, d); if (lane >= d) s += u; }
  __shared__ int wsum[4];
  if (lane == 63) wsum[w] = s;
  __syncthreads();
  int add = 0;
  #pragma unroll
  for (int k = 0; k < 4; ++k) if (k < w) add += wsum[k];
  s += add;
  if (i < n) rs[i + 1] = s;
  if (t == 255) part[b] = s;
}

// exclusive scan of part[0..nb) (nb<=256), single block
__global__ __launch_bounds__(256)
void k_scan2(int* __restrict__ part, int nb){
  const int t = threadIdx.x;
  int v = (t < nb) ? part[t] : 0;
  const int lane = t & 63, w = t >> 6;
  int s = v;
  #pragma unroll
  for (int d = 1; d < 64; d <<= 1){ int u = __shfl_up(s, d); if (lane >= d) s += u; }
  __shared__ int wsum[4];
  if (lane == 63) wsum[w] = s;
  __syncthreads();
  int add = 0;
  #pragma unroll
  for (int k = 0; k < 4; ++k) if (k < w) add += wsum[k];
  s += add;
  if (t < nb) part[t] = s - v;
}

__global__ __launch_bounds__(256)
void k_scan3(int* __restrict__ rs, const int* __restrict__ part, int n){
  const int i = blockIdx.x * 256 + threadIdx.x;
  if (i < n) rs[i + 1] += part[blockIdx.x];
  if (i == 0) rs[0] = 0;
}

__global__ void k_scatter(const int* __restrict__ row, const int* __restrict__ col,
                          const float* __restrict__ val, const int* __restrict__ start,
                          int* __restrict__ cursor, int2* __restrict__ out){
  int e = blockIdx.x * blockDim.x + threadIdx.x;
  if (e >= NE) return;
  int r = row[e];
  int pos = start[r] + atomicAdd(&cursor[r], 1);
  out[pos] = make_int2(col[e], __float_as_int(val[e]));
}

// ---------------- fp32 -> split bf16 [hi | lo] conversion ----------------
// dst [Mpad][2*Kp] bf16 (cols [0,Kp)=hi, [Kp,2Kp)=lo). Grid covers Mpad*Kp/4 quads.

__global__ __launch_bounds__(256)
void conv_split(const float* __restrict__ src, __bf16* __restrict__ dst,
                int M, int K, int Kp){
  const int q = blockIdx.x * 256 + threadIdx.x;
  const int perRow = Kp >> 2;
  const int r = q / perRow;
  const int k = (q - r * perRow) << 2;
  float4 v = make_float4(0.f, 0.f, 0.f, 0.f);
  if (r < M && k < K) v = *(const float4*)(src + (size_t)r * K + k);
  bf16x4 h, l;
  {
    float e0 = v.x, e1 = v.y, e2 = v.z, e3 = v.w;
    __bf16 h0 = (__bf16)e0, h1 = (__bf16)e1, h2 = (__bf16)e2, h3 = (__bf16)e3;
    h[0] = h0; h[1] = h1; h[2] = h2; h[3] = h3;
    l[0] = (__bf16)(e0 - (float)h0); l[1] = (__bf16)(e1 - (float)h1);
    l[2] = (__bf16)(e2 - (float)h2); l[3] = (__bf16)(e3 - (float)h3);
  }
  *(bf16x4*)(dst + (size_t)r * 2 * Kp + k) = h;
  *(bf16x4*)(dst + (size_t)r * 2 * Kp + Kp + k) = l;
}

__global__ void k_zero_bf16(__bf16* __restrict__ p, int n4){
  int i = blockIdx.x * blockDim.x + threadIdx.x;
  if (i < n4){ bf16x4 z = {}; *(bf16x4*)(p + (size_t)i * 4) = z; }
}

// ---------------- split-bf16 MFMA GEMM ----------------
// C[M][N] (f32) = A*B^T in split precision via concatenated K:
// virtual k-tile kt in [0,3*SEC): s0: Ahi*Bhi, s1: Alo*Bhi, s2: Ahi*Blo.
// A [Mpad][ld] bf16 (hi cols [0,SEC*64), lo cols [SEC*64,2*SEC*64)), B same.
// Tile BM=128 BN=64 BK=64; 256 thr = 4 waves (2x2); mfma 16x16x32;
// LDS linear + XOR-swizzled global source (T2 / rule #21).

template<int SEC>
__global__ __launch_bounds__(256)
void gemm_mfma(const __bf16* __restrict__ A, const __bf16* __restrict__ B,
               float* __restrict__ C, int M, int N, int ld){
  __shared__ char ldsbuf[49152];                 // 2 x (16KB A + 8KB B)
  const int tid = threadIdx.x;
  const int lane = tid & 63;
  const int bn = blockIdx.x * 64;
  const int bm = blockIdx.y * 128;
  const int wr = (tid >> 7) & 1;                 // wave row (0/1)
  const int wc = (tid >> 6) & 1;                 // wave col (0/1)

  f32x4 acc[4][2];
  #pragma unroll
  for (int i = 0; i < 4; ++i)
    #pragma unroll
    for (int j = 0; j < 2; ++j) acc[i][j] = (f32x4){0.f, 0.f, 0.f, 0.f};

  auto stage = [&](int kt, int sel){
    const int akt = (kt < 2 * SEC) ? kt : kt - 2 * SEC;
    const int bkt = (kt < SEC) ? kt : kt - SEC;
    char* lb = ldsbuf + sel * 24576;
    #pragma unroll
    for (int i = 0; i < 4; ++i){                 // A tile 16KB
      const int d = i * 4096 + tid * 16;
      const int row = d >> 7;
      const int colb = (d & 127) ^ ((row & 7) << 4);
      const __bf16* gp = A + (size_t)(bm + row) * ld + akt * 64 + (colb >> 1);
      gload16(gp, lb + i * 4096 + (tid & 192) * 16);
    }
    #pragma unroll
    for (int i = 0; i < 2; ++i){                 // B tile 8KB
      const int d = i * 4096 + tid * 16;
      const int row = d >> 7;
      const int colb = (d & 127) ^ ((row & 7) << 4);
      const __bf16* gp = B + (size_t)(bn + row) * ld + bkt * 64 + (colb >> 1);
      gload16(gp, lb + 16384 + i * 4096 + (tid & 192) * 16);
    }
  };

  auto compute = [&](int sel){
    const char* lA = ldsbuf + sel * 24576;
    const char* lB = lA + 16384;
    #pragma unroll
    for (int c = 0; c < 2; ++c){
      bf16x8 av[4], bv[2];
      #pragma unroll
      for (int i = 0; i < 4; ++i){
        const int row = wr * 64 + i * 16 + (lane & 15);
        const int colb = (c * 64 + ((lane >> 4) << 4)) ^ ((row & 7) << 4);
        av[i] = *(const bf16x8*)(lA + row * 128 + colb);
      }
      #pragma unroll
      for (int j = 0; j < 2; ++j){
        const int row = wc * 32 + j * 16 + (lane & 15);
        const int colb = (c * 64 + ((lane >> 4) << 4)) ^ ((row & 7) << 4);
        bv[j] = *(const bf16x8*)(lB + row * 128 + colb);
      }
      #pragma unroll
      for (int i = 0; i < 4; ++i)
        #pragma unroll
        for (int j = 0; j < 2; ++j)
          acc[i][j] = __builtin_amdgcn_mfma_f32_16x16x32_bf16(av[i], bv[j], acc[i][j], 0, 0, 0);
    }
  };

  stage(0, 0);
  for (int kt = 0; kt < 3 * SEC; ++kt){
    __syncthreads();                             // drains vmcnt: stage(kt) complete
    if (kt + 1 < 3 * SEC) stage(kt + 1, (kt + 1) & 1);
    compute(kt & 1);
  }

  #pragma unroll
  for (int i = 0; i < 4; ++i){
    #pragma unroll
    for (int r = 0; r < 4; ++r){
      const int row = bm + wr * 64 + i * 16 + ((lane >> 4) << 2) + r;
      if (row < M){
        #pragma unroll
        for (int j = 0; j < 2; ++j)
          C[(size_t)row * N + bn + wc * 32 + j * 16 + (lane & 15)] = acc[i][j][r];
      }
    }
  }
}

// ---------------- SpMM (CSR, wave per row) ----------------

// D=256: out = split-bf16 of relu(A*H + b1), written as [NNpad][512] (hi|lo)
__global__ __launch_bounds__(256)
void spmm_bias_relu_split(const int2* __restrict__ ecv, const int* __restrict__ start,
                          const float* __restrict__ H, const float* __restrict__ bias,
                          __bf16* __restrict__ out){
  const int w = (blockIdx.x * 256 + threadIdx.x) >> 6;
  const int lane = threadIdx.x & 63;
  if (w >= NN) return;
  const int s = start[w], e = start[w + 1];
  float4 acc = make_float4(0.f, 0.f, 0.f, 0.f);
  for (int p = s; p < e; ++p){
    const int2 cv = ecv[p];
    const float v = __int_as_float(cv.y);
    const float4 h = *(const float4*)(H + (size_t)cv.x * 256 + lane * 4);
    acc.x = fmaf(v, h.x, acc.x);
    acc.y = fmaf(v, h.y, acc.y);
    acc.z = fmaf(v, h.z, acc.z);
    acc.w = fmaf(v, h.w, acc.w);
  }
  const float4 b = *(const float4*)(bias + lane * 4);
  float e0 = fmaxf(acc.x + b.x, 0.f);
  float e1 = fmaxf(acc.y + b.y, 0.f);
  float e2 = fmaxf(acc.z + b.z, 0.f);
  float e3 = fmaxf(acc.w + b.w, 0.f);
  bf16x4 hv, lv;
  __bf16 h0 = (__bf16)e0, h1 = (__bf16)e1, h2 = (__bf16)e2, h3 = (__bf16)e3;
  hv[0] = h0; hv[1] = h1; hv[2] = h2; hv[3] = h3;
  lv[0] = (__bf16)(e0 - (float)h0); lv[1] = (__bf16)(e1 - (float)h1);
  lv[2] = (__bf16)(e2 - (float)h2); lv[3] = (__bf16)(e3 - (float)h3);
  *(bf16x4*)(out + (size_t)w * 512 + lane * 4) = hv;
  *(bf16x4*)(out + (size_t)w * 512 + 256 + lane * 4) = lv;
}

__global__ __launch_bounds__(256)
void spmm_bias_norm_d128(const int2* __restrict__ ecv, const int* __restrict__ start,
                         const float* __restrict__ H, const float* __restrict__ bias,
                         float* __restrict__ out){
  const int w = (blockIdx.x * 256 + threadIdx.x) >> 6;
  const int lane = threadIdx.x & 63;
  if (w >= NN) return;
  const int s = start[w], e = start[w + 1];
  float2 acc = make_float2(0.f, 0.f);
  for (int p = s; p < e; ++p){
    const int2 cv = ecv[p];
    const float v = __int_as_float(cv.y);
    const float2 h = *(const float2*)(H + (size_t)cv.x * 128 + lane * 2);
    acc.x = fmaf(v, h.x, acc.x);
    acc.y = fmaf(v, h.y, acc.y);
  }
  acc.x += bias[lane * 2 + 0];
  acc.y += bias[lane * 2 + 1];
  float ss = acc.x * acc.x + acc.y * acc.y;
  #pragma unroll
  for (int m = 1; m < 64; m <<= 1) ss += __shfl_xor(ss, m);
  const float inv = 1.f / fmaxf(sqrtf(ss), 1e-12f);
  *(float2*)(out + (size_t)w * 128 + lane * 2) = make_float2(acc.x * inv, acc.y * inv);
}

// ---------------- launch ----------------
// ws layout (bytes):
//  R1 @ 0         (64,061,440): Abig1 [50048][640]bf16 -> later Abig2 [50048][512]bf16
//  R2 @ 64061440  (51,200,000): h1 [50000][256]f32     -> later h3 [50000][128]f32
//  R3 @115261440  (   327,680): Bbig1 [256][640]       -> later Bbig2 [128][512]
//  ecv @115589120 ( 6,400,000)
//  rs  @121989120 (   200,016)
//  part@122189136 (       784+pad)
//  cur @122189920 (   200,000)   total ~122.4 MB

extern "C" void kernel_launch(void* const* d_in, const int* in_sizes, int n_in,
                              void* d_out, int out_size, void* d_ws, size_t ws_size,
                              hipStream_t stream){
  const float* x    = (const float*)d_in[0];
  const int*   erow = (const int*)d_in[1];
  const int*   ecol = (const int*)d_in[2];
  const float* evalv= (const float*)d_in[3];
  const float* W1   = (const float*)d_in[4];
  const float* b1   = (const float*)d_in[5];
  const float* W2   = (const float*)d_in[6];
  const float* b2   = (const float*)d_in[7];
  float* out = (float*)d_out;

  char* ws = (char*)d_ws;
  __bf16* Abig = (__bf16*)(ws);                      // Abig1 then Abig2
  float*  h1   = (float*)(ws + 64061440);            // then h3
  __bf16* Bbig = (__bf16*)(ws + 115261440);          // Bbig1 then Bbig2
  int2*   ecv  = (int2*)(ws + 115589120);
  int*    rs   = (int*)(ws + 121989120);
  int*    part = (int*)(ws + 122189136);
  int*    cur  = (int*)(ws + 122189920);
  float*  h3   = h1;

  // CSR build
  k_zero_i32<<<196, 256, 0, stream>>>(cur, NN);
  k_hist<<<3125, 256, 0, stream>>>(erow, cur);
  k_scan1<<<196, 256, 0, stream>>>(cur, rs, part, NN);
  k_scan2<<<1, 256, 0, stream>>>(part, 196);
  k_scan3<<<196, 256, 0, stream>>>(rs, part, NN);
  k_zero_i32<<<196, 256, 0, stream>>>(cur, NN);
  k_scatter<<<3125, 256, 0, stream>>>(erow, ecol, evalv, rs, cur, ecv);

  // layer 1: h1 = x @ W1^T  (split-bf16 MFMA, K=300 -> Kp=320, SEC=5)
  conv_split<<<15640, 256, 0, stream>>>(x, Abig, NN, 300, 320);
  conv_split<<<80, 256, 0, stream>>>(W1, Bbig, 256, 300, 320);
  gemm_mfma<5><<<dim3(4, 391), 256, 0, stream>>>(Abig, Bbig, h1, NN, 256, 640);
  // h2 = relu(A*h1 + b1), emitted directly as split bf16 Abig2 [50048][512]
  spmm_bias_relu_split<<<12500, 256, 0, stream>>>(ecv, rs, h1, b1, Abig);
  k_zero_bf16<<<24, 256, 0, stream>>>(Abig + (size_t)NN * 512, 6144);  // pad rows

  // layer 2: h3 = h2 @ W2^T (Kp=256, SEC=4)
  conv_split<<<32, 256, 0, stream>>>(W2, Bbig, 128, 256, 256);
  gemm_mfma<4><<<dim3(2, 391), 256, 0, stream>>>(Abig, Bbig, h3, NN, 128, 512);
  // out = l2norm(A*h3 + b2)
  spmm_bias_norm_d128<<<12500, 256, 0, stream>>>(ecv, rs, h3, b2, out);
}

// Round 3
// 278.683 us; speedup vs baseline: 1.8542x; 1.5207x over previous
//
#include <hip/hip_runtime.h>
#include <math.h>

#define NN 50000
#define NE 800000

typedef __bf16 bf16x8 __attribute__((ext_vector_type(8)));
typedef __bf16 bf16x4 __attribute__((ext_vector_type(4)));
typedef __bf16 bf16x2 __attribute__((ext_vector_type(2)));
typedef float f32x4 __attribute__((ext_vector_type(4)));

__device__ __forceinline__ void gload16(const void* g, void* l){
  __builtin_amdgcn_global_load_lds((const __attribute__((address_space(1))) void*)g,
                                   (__attribute__((address_space(3))) void*)l, 16, 0, 0);
}

// ---------------- CSR build ----------------

__global__ void k_zero_i32(int* __restrict__ p, int n){
  int i = blockIdx.x * blockDim.x + threadIdx.x;
  if (i < n) p[i] = 0;
}

__global__ void k_hist(const int* __restrict__ row, int* __restrict__ cnt){
  int e = blockIdx.x * blockDim.x + threadIdx.x;
  if (e < NE) atomicAdd(&cnt[row[e]], 1);
}

__global__ __launch_bounds__(256)
void k_scan1(const int* __restrict__ cnt, int* __restrict__ rs, int* __restrict__ part, int n){
  const int t = threadIdx.x, b = blockIdx.x;
  const int i = b * 256 + t;
  int v = (i < n) ? cnt[i] : 0;
  const int lane = t & 63, w = t >> 6;
  int s = v;
  #pragma unroll
  for (int d = 1; d < 64; d <<= 1){ int u = __shfl_up(s, d); if (lane >= d) s += u; }
  __shared__ int wsum[4];
  if (lane == 63) wsum[w] = s;
  __syncthreads();
  int add = 0;
  #pragma unroll
  for (int k = 0; k < 4; ++k) if (k < w) add += wsum[k];
  s += add;
  if (i < n) rs[i + 1] = s;
  if (t == 255) part[b] = s;
}

__global__ __launch_bounds__(256)
void k_scan2(int* __restrict__ part, int nb){
  const int t = threadIdx.x;
  int v = (t < nb) ? part[t] : 0;
  const int lane = t & 63, w = t >> 6;
  int s = v;
  #pragma unroll
  for (int d = 1; d < 64; d <<= 1){ int u = __shfl_up(s, d); if (lane >= d) s += u; }
  __shared__ int wsum[4];
  if (lane == 63) wsum[w] = s;
  __syncthreads();
  int add = 0;
  #pragma unroll
  for (int k = 0; k < 4; ++k) if (k < w) add += wsum[k];
  s += add;
  if (t < nb) part[t] = s - v;
}

__global__ __launch_bounds__(256)
void k_scan3(int* __restrict__ rs, const int* __restrict__ part, int n){
  const int i = blockIdx.x * 256 + threadIdx.x;
  if (i < n) rs[i + 1] += part[blockIdx.x];
  if (i == 0) rs[0] = 0;
}

__global__ void k_scatter(const int* __restrict__ row, const int* __restrict__ col,
                          const float* __restrict__ val, const int* __restrict__ start,
                          int* __restrict__ cursor, int2* __restrict__ out){
  int e = blockIdx.x * blockDim.x + threadIdx.x;
  if (e >= NE) return;
  int r = row[e];
  int pos = start[r] + atomicAdd(&cursor[r], 1);
  out[pos] = make_int2(col[e], __float_as_int(val[e]));
}

// ---------------- fp32 -> bf16 conversion (padded [grid-covered rows][Kp]) ----------------

__global__ __launch_bounds__(256)
void conv_bf16(const float* __restrict__ src, __bf16* __restrict__ dst,
               int M, int K, int Kp){
  const int q = blockIdx.x * 256 + threadIdx.x;
  const int perRow = Kp >> 2;
  const int r = q / perRow;
  const int k = (q - r * perRow) << 2;
  float4 v = make_float4(0.f, 0.f, 0.f, 0.f);
  if (r < M && k < K) v = *(const float4*)(src + (size_t)r * K + k);   // K % 4 == 0
  bf16x4 o;
  o[0] = (__bf16)v.x; o[1] = (__bf16)v.y; o[2] = (__bf16)v.z; o[3] = (__bf16)v.w;
  *(bf16x4*)(dst + (size_t)r * Kp + k) = o;
}

__global__ void k_zero_bf16(__bf16* __restrict__ p, int n4){
  int i = blockIdx.x * blockDim.x + threadIdx.x;
  if (i < n4){ bf16x4 z = {}; *(bf16x4*)(p + (size_t)i * 4) = z; }
}

// ---------------- bf16 MFMA GEMM, bf16 output ----------------
// C[Mpad][N] bf16 = A[Mpad][ld] * B[N][ld]^T. BM=128 BN=64 BK=64, 4 waves 2x2,
// mfma 16x16x32, LDS linear dest + XOR-swizzled global src (T2/rule #21),
// LDS-transposed epilogue for coalesced bf16x8 stores. Grid y covers Mpad.

template<int KT>
__global__ __launch_bounds__(256)
void gemm_bf16(const __bf16* __restrict__ A, const __bf16* __restrict__ B,
               __bf16* __restrict__ C, int ld, int N){
  __shared__ char ldsbuf[49152];                 // 2 x (16KB A + 8KB B); epi reuses 34.8KB
  const int tid = threadIdx.x;
  const int lane = tid & 63;
  const int bn = blockIdx.x * 64;
  const int bm = blockIdx.y * 128;
  const int wr = (tid >> 7) & 1;
  const int wc = (tid >> 6) & 1;

  f32x4 acc[4][2];
  #pragma unroll
  for (int i = 0; i < 4; ++i)
    #pragma unroll
    for (int j = 0; j < 2; ++j) acc[i][j] = (f32x4){0.f, 0.f, 0.f, 0.f};

  auto stage = [&](int kt, int sel){
    char* lb = ldsbuf + sel * 24576;
    #pragma unroll
    for (int i = 0; i < 4; ++i){                 // A tile 16KB (128 rows x 128B)
      const int d = i * 4096 + tid * 16;
      const int row = d >> 7;
      const int colb = (d & 127) ^ ((row & 7) << 4);
      const __bf16* gp = A + (size_t)(bm + row) * ld + kt * 64 + (colb >> 1);
      gload16(gp, lb + i * 4096 + (tid & 192) * 16);
    }
    #pragma unroll
    for (int i = 0; i < 2; ++i){                 // B tile 8KB (64 rows x 128B)
      const int d = i * 4096 + tid * 16;
      const int row = d >> 7;
      const int colb = (d & 127) ^ ((row & 7) << 4);
      const __bf16* gp = B + (size_t)(bn + row) * ld + kt * 64 + (colb >> 1);
      gload16(gp, lb + 16384 + i * 4096 + (tid & 192) * 16);
    }
  };

  auto compute = [&](int sel){
    const char* lA = ldsbuf + sel * 24576;
    const char* lB = lA + 16384;
    #pragma unroll
    for (int c = 0; c < 2; ++c){
      bf16x8 av[4], bv[2];
      #pragma unroll
      for (int i = 0; i < 4; ++i){
        const int row = wr * 64 + i * 16 + (lane & 15);
        const int colb = (c * 64 + ((lane >> 4) << 4)) ^ ((row & 7) << 4);
        av[i] = *(const bf16x8*)(lA + row * 128 + colb);
      }
      #pragma unroll
      for (int j = 0; j < 2; ++j){
        const int row = wc * 32 + j * 16 + (lane & 15);
        const int colb = (c * 64 + ((lane >> 4) << 4)) ^ ((row & 7) << 4);
        bv[j] = *(const bf16x8*)(lB + row * 128 + colb);
      }
      #pragma unroll
      for (int i = 0; i < 4; ++i)
        #pragma unroll
        for (int j = 0; j < 2; ++j)
          acc[i][j] = __builtin_amdgcn_mfma_f32_16x16x32_bf16(av[i], bv[j], acc[i][j], 0, 0, 0);
    }
  };

  stage(0, 0);
  for (int kt = 0; kt < KT; ++kt){
    __syncthreads();
    if (kt + 1 < KT) stage(kt + 1, (kt + 1) & 1);
    compute(kt & 1);
  }

  // epilogue: acc -> LDS f32 [128][68] -> coalesced bf16x8 stores
  __syncthreads();
  float* lw = (float*)ldsbuf;
  #pragma unroll
  for (int i = 0; i < 4; ++i)
    #pragma unroll
    for (int j = 0; j < 2; ++j)
      #pragma unroll
      for (int r = 0; r < 4; ++r){
        const int row = wr * 64 + i * 16 + ((lane >> 4) << 2) + r;
        const int col = wc * 32 + j * 16 + (lane & 15);
        lw[row * 68 + col] = acc[i][j][r];
      }
  __syncthreads();
  #pragma unroll
  for (int p = 0; p < 4; ++p){
    const int row = p * 32 + (tid >> 3);
    const int col8 = (tid & 7) * 8;
    const float4 v0 = *(const float4*)&lw[row * 68 + col8];
    const float4 v1 = *(const float4*)&lw[row * 68 + col8 + 4];
    bf16x8 o;
    o[0] = (__bf16)v0.x; o[1] = (__bf16)v0.y; o[2] = (__bf16)v0.z; o[3] = (__bf16)v0.w;
    o[4] = (__bf16)v1.x; o[5] = (__bf16)v1.y; o[6] = (__bf16)v1.z; o[7] = (__bf16)v1.w;
    *(bf16x8*)(C + (size_t)(bm + row) * N + bn + col8) = o;
  }
}

// ---------------- SpMM (CSR, wave per row, bf16 gather) ----------------

__global__ __launch_bounds__(256)
void spmm_bias_relu_b16(const int2* __restrict__ ecv, const int* __restrict__ start,
                        const __bf16* __restrict__ H, const float* __restrict__ bias,
                        __bf16* __restrict__ out){
  const int w = (blockIdx.x * 256 + threadIdx.x) >> 6;
  const int lane = threadIdx.x & 63;
  if (w >= NN) return;
  const int s = start[w], e = start[w + 1];
  float4 acc = make_float4(0.f, 0.f, 0.f, 0.f);
  for (int base = s; base < e; base += 64){
    int2 cv = make_int2(0, 0);
    if (base + lane < e) cv = ecv[base + lane];
    const int m = min(64, e - base);
    for (int j = 0; j < m; ++j){
      const int col = __shfl(cv.x, j);
      const float v = __int_as_float(__shfl(cv.y, j));
      const bf16x4 h = *(const bf16x4*)(H + (size_t)col * 256 + lane * 4);
      acc.x = fmaf(v, (float)h[0], acc.x);
      acc.y = fmaf(v, (float)h[1], acc.y);
      acc.z = fmaf(v, (float)h[2], acc.z);
      acc.w = fmaf(v, (float)h[3], acc.w);
    }
  }
  const float4 b = *(const float4*)(bias + lane * 4);
  bf16x4 o;
  o[0] = (__bf16)fmaxf(acc.x + b.x, 0.f);
  o[1] = (__bf16)fmaxf(acc.y + b.y, 0.f);
  o[2] = (__bf16)fmaxf(acc.z + b.z, 0.f);
  o[3] = (__bf16)fmaxf(acc.w + b.w, 0.f);
  *(bf16x4*)(out + (size_t)w * 256 + lane * 4) = o;
}

__global__ __launch_bounds__(256)
void spmm_bias_norm_b16(const int2* __restrict__ ecv, const int* __restrict__ start,
                        const __bf16* __restrict__ H, const float* __restrict__ bias,
                        float* __restrict__ out){
  const int w = (blockIdx.x * 256 + threadIdx.x) >> 6;
  const int lane = threadIdx.x & 63;
  if (w >= NN) return;
  const int s = start[w], e = start[w + 1];
  float2 acc = make_float2(0.f, 0.f);
  for (int base = s; base < e; base += 64){
    int2 cv = make_int2(0, 0);
    if (base + lane < e) cv = ecv[base + lane];
    const int m = min(64, e - base);
    for (int j = 0; j < m; ++j){
      const int col = __shfl(cv.x, j);
      const float v = __int_as_float(__shfl(cv.y, j));
      const bf16x2 h = *(const bf16x2*)(H + (size_t)col * 128 + lane * 2);
      acc.x = fmaf(v, (float)h[0], acc.x);
      acc.y = fmaf(v, (float)h[1], acc.y);
    }
  }
  acc.x += bias[lane * 2 + 0];
  acc.y += bias[lane * 2 + 1];
  float ss = acc.x * acc.x + acc.y * acc.y;
  #pragma unroll
  for (int m2 = 1; m2 < 64; m2 <<= 1) ss += __shfl_xor(ss, m2);
  const float inv = 1.f / fmaxf(sqrtf(ss), 1e-12f);
  *(float2*)(out + (size_t)w * 128 + lane * 2) = make_float2(acc.x * inv, acc.y * inv);
}

// ---------------- launch ----------------
// ws layout (bytes):
//  xb  @ 0          [50048][320] bf16 = 32,030,720
//  W1b @ 32030720   [256][320]  bf16 =    163,840
//  W2b @ 32194560   [128][256]  bf16 =     65,536
//  h1  @ 32260096   [50048][256] bf16 = 25,624,576
//  h2  @ 57884672   [50048][256] bf16 = 25,624,576
//  h3  @ 83509248   [50048][128] bf16 = 12,812,288
//  ecv @ 96321536   800000 int2       =  6,400,000
//  rs  @ 102721536  50001 int         =    200,016
//  part@ 102921552  ~200 int (pad)
//  cur @ 102922368  50000 int         =    200,000   total ~103.1 MB

extern "C" void kernel_launch(void* const* d_in, const int* in_sizes, int n_in,
                              void* d_out, int out_size, void* d_ws, size_t ws_size,
                              hipStream_t stream){
  const float* x    = (const float*)d_in[0];
  const int*   erow = (const int*)d_in[1];
  const int*   ecol = (const int*)d_in[2];
  const float* evalv= (const float*)d_in[3];
  const float* W1   = (const float*)d_in[4];
  const float* b1   = (const float*)d_in[5];
  const float* W2   = (const float*)d_in[6];
  const float* b2   = (const float*)d_in[7];
  float* out = (float*)d_out;

  char* ws = (char*)d_ws;
  __bf16* xb  = (__bf16*)(ws);
  __bf16* W1b = (__bf16*)(ws + 32030720);
  __bf16* W2b = (__bf16*)(ws + 32194560);
  __bf16* h1  = (__bf16*)(ws + 32260096);
  __bf16* h2  = (__bf16*)(ws + 57884672);
  __bf16* h3  = (__bf16*)(ws + 83509248);
  int2*   ecv = (int2*)(ws + 96321536);
  int*    rs  = (int*)(ws + 102721536);
  int*    part= (int*)(ws + 102921552);
  int*    cur = (int*)(ws + 102922368);

  // CSR build
  k_zero_i32<<<196, 256, 0, stream>>>(cur, NN);
  k_hist<<<3125, 256, 0, stream>>>(erow, cur);
  k_scan1<<<196, 256, 0, stream>>>(cur, rs, part, NN);
  k_scan2<<<1, 256, 0, stream>>>(part, 196);
  k_scan3<<<196, 256, 0, stream>>>(rs, part, NN);
  k_zero_i32<<<196, 256, 0, stream>>>(cur, NN);
  k_scatter<<<3125, 256, 0, stream>>>(erow, ecol, evalv, rs, cur, ecv);

  // conversions
  conv_bf16<<<15640, 256, 0, stream>>>(x, xb, NN, 300, 320);    // covers 50048 rows
  conv_bf16<<<80, 256, 0, stream>>>(W1, W1b, 256, 300, 320);
  conv_bf16<<<32, 256, 0, stream>>>(W2, W2b, 128, 256, 256);

  // layer 1: h1 = bf16(xb @ W1b^T); h2 = bf16(relu(A*h1 + b1))
  gemm_bf16<5><<<dim3(4, 391), 256, 0, stream>>>(xb, W1b, h1, 320, 256);
  spmm_bias_relu_b16<<<12500, 256, 0, stream>>>(ecv, rs, h1, b1, h2);
  k_zero_bf16<<<12, 256, 0, stream>>>(h2 + (size_t)NN * 256, 3072);   // pad rows

  // layer 2: h3 = bf16(h2 @ W2b^T); out = l2norm(A*h3 + b2)
  gemm_bf16<4><<<dim3(2, 391), 256, 0, stream>>>(h2, W2b, h3, 256, 128);
  spmm_bias_norm_b16<<<12500, 256, 0, stream>>>(ecv, rs, h3, b2, out);
}

// Round 4
// 247.124 us; speedup vs baseline: 2.0910x; 1.1277x over previous
//
#include <hip/hip_runtime.h>
#include <math.h>

#define NN 50000
#define NE 800000

typedef __bf16 bf16x8 __attribute__((ext_vector_type(8)));
typedef __bf16 bf16x4 __attribute__((ext_vector_type(4)));
typedef float f32x4 __attribute__((ext_vector_type(4)));

__device__ __forceinline__ void gload16(const void* g, void* l){
  __builtin_amdgcn_global_load_lds((const __attribute__((address_space(1))) void*)g,
                                   (__attribute__((address_space(3))) void*)l, 16, 0, 0);
}

// ---------------- CSR build ----------------

__global__ void k_zero_i32(int* __restrict__ p, int n){
  int i = blockIdx.x * blockDim.x + threadIdx.x;
  if (i < n) p[i] = 0;
}

__global__ void k_hist(const int* __restrict__ row, int* __restrict__ cnt){
  int e = blockIdx.x * blockDim.x + threadIdx.x;
  if (e < NE) atomicAdd(&cnt[row[e]], 1);
}

__global__ __launch_bounds__(256)
void k_scan1(const int* __restrict__ cnt, int* __restrict__ rs, int* __restrict__ part, int n){
  const int t = threadIdx.x, b = blockIdx.x;
  const int i = b * 256 + t;
  int v = (i < n) ? cnt[i] : 0;
  const int lane = t & 63, w = t >> 6;
  int s = v;
  #pragma unroll
  for (int d = 1; d < 64; d <<= 1){ int u = __shfl_up(s, d); if (lane >= d) s += u; }
  __shared__ int wsum[4];
  if (lane == 63) wsum[w] = s;
  __syncthreads();
  int add = 0;
  #pragma unroll
  for (int k = 0; k < 4; ++k) if (k < w) add += wsum[k];
  s += add;
  if (i < n) rs[i + 1] = s;
  if (t == 255) part[b] = s;
}

__global__ __launch_bounds__(256)
void k_scan2(int* __restrict__ part, int nb){
  const int t = threadIdx.x;
  int v = (t < nb) ? part[t] : 0;
  const int lane = t & 63, w = t >> 6;
  int s = v;
  #pragma unroll
  for (int d = 1; d < 64; d <<= 1){ int u = __shfl_up(s, d); if (lane >= d) s += u; }
  __shared__ int wsum[4];
  if (lane == 63) wsum[w] = s;
  __syncthreads();
  int add = 0;
  #pragma unroll
  for (int k = 0; k < 4; ++k) if (k < w) add += wsum[k];
  s += add;
  if (t < nb) part[t] = s - v;
}

__global__ __launch_bounds__(256)
void k_scan3(int* __restrict__ rs, const int* __restrict__ part, int n){
  const int i = blockIdx.x * 256 + threadIdx.x;
  if (i < n) rs[i + 1] += part[blockIdx.x];
  if (i == 0) rs[0] = 0;
}

__global__ void k_scatter(const int* __restrict__ row, const int* __restrict__ col,
                          const float* __restrict__ val, const int* __restrict__ start,
                          int* __restrict__ cursor, int2* __restrict__ out){
  int e = blockIdx.x * blockDim.x + threadIdx.x;
  if (e >= NE) return;
  int r = row[e];
  int pos = start[r] + atomicAdd(&cursor[r], 1);
  out[pos] = make_int2(col[e], __float_as_int(val[e]));
}

// ---------------- fp32 -> bf16 conversion ----------------

__global__ __launch_bounds__(256)
void conv_bf16(const float* __restrict__ src, __bf16* __restrict__ dst,
               int M, int K, int Kp){
  const int q = blockIdx.x * 256 + threadIdx.x;
  const int perRow = Kp >> 2;
  const int r = q / perRow;
  const int k = (q - r * perRow) << 2;
  float4 v = make_float4(0.f, 0.f, 0.f, 0.f);
  if (r < M && k < K) v = *(const float4*)(src + (size_t)r * K + k);   // K % 4 == 0
  bf16x4 o;
  o[0] = (__bf16)v.x; o[1] = (__bf16)v.y; o[2] = (__bf16)v.z; o[3] = (__bf16)v.w;
  *(bf16x4*)(dst + (size_t)r * Kp + k) = o;
}

__global__ void k_zero_bf16(__bf16* __restrict__ p, int n4){
  int i = blockIdx.x * blockDim.x + threadIdx.x;
  if (i < n4){ bf16x4 z = {}; *(bf16x4*)(p + (size_t)i * 4) = z; }
}

// ---------------- bf16 MFMA GEMM, bf16 output ----------------

template<int KT>
__global__ __launch_bounds__(256)
void gemm_bf16(const __bf16* __restrict__ A, const __bf16* __restrict__ B,
               __bf16* __restrict__ C, int ld, int N){
  __shared__ char ldsbuf[49152];                 // 2 x (16KB A + 8KB B); epi reuses 34.8KB
  const int tid = threadIdx.x;
  const int lane = tid & 63;
  const int bn = blockIdx.x * 64;
  const int bm = blockIdx.y * 128;
  const int wr = (tid >> 7) & 1;
  const int wc = (tid >> 6) & 1;

  f32x4 acc[4][2];
  #pragma unroll
  for (int i = 0; i < 4; ++i)
    #pragma unroll
    for (int j = 0; j < 2; ++j) acc[i][j] = (f32x4){0.f, 0.f, 0.f, 0.f};

  auto stage = [&](int kt, int sel){
    char* lb = ldsbuf + sel * 24576;
    #pragma unroll
    for (int i = 0; i < 4; ++i){                 // A tile 16KB (128 rows x 128B)
      const int d = i * 4096 + tid * 16;
      const int row = d >> 7;
      const int colb = (d & 127) ^ ((row & 7) << 4);
      const __bf16* gp = A + (size_t)(bm + row) * ld + kt * 64 + (colb >> 1);
      gload16(gp, lb + i * 4096 + (tid & 192) * 16);
    }
    #pragma unroll
    for (int i = 0; i < 2; ++i){                 // B tile 8KB (64 rows x 128B)
      const int d = i * 4096 + tid * 16;
      const int row = d >> 7;
      const int colb = (d & 127) ^ ((row & 7) << 4);
      const __bf16* gp = B + (size_t)(bn + row) * ld + kt * 64 + (colb >> 1);
      gload16(gp, lb + 16384 + i * 4096 + (tid & 192) * 16);
    }
  };

  auto compute = [&](int sel){
    const char* lA = ldsbuf + sel * 24576;
    const char* lB = lA + 16384;
    #pragma unroll
    for (int c = 0; c < 2; ++c){
      bf16x8 av[4], bv[2];
      #pragma unroll
      for (int i = 0; i < 4; ++i){
        const int row = wr * 64 + i * 16 + (lane & 15);
        const int colb = (c * 64 + ((lane >> 4) << 4)) ^ ((row & 7) << 4);
        av[i] = *(const bf16x8*)(lA + row * 128 + colb);
      }
      #pragma unroll
      for (int j = 0; j < 2; ++j){
        const int row = wc * 32 + j * 16 + (lane & 15);
        const int colb = (c * 64 + ((lane >> 4) << 4)) ^ ((row & 7) << 4);
        bv[j] = *(const bf16x8*)(lB + row * 128 + colb);
      }
      #pragma unroll
      for (int i = 0; i < 4; ++i)
        #pragma unroll
        for (int j = 0; j < 2; ++j)
          acc[i][j] = __builtin_amdgcn_mfma_f32_16x16x32_bf16(av[i], bv[j], acc[i][j], 0, 0, 0);
    }
  };

  stage(0, 0);
  for (int kt = 0; kt < KT; ++kt){
    __syncthreads();
    if (kt + 1 < KT) stage(kt + 1, (kt + 1) & 1);
    compute(kt & 1);
  }

  // epilogue: acc -> LDS f32 [128][68] -> coalesced bf16x8 stores
  __syncthreads();
  float* lw = (float*)ldsbuf;
  #pragma unroll
  for (int i = 0; i < 4; ++i)
    #pragma unroll
    for (int j = 0; j < 2; ++j)
      #pragma unroll
      for (int r = 0; r < 4; ++r){
        const int row = wr * 64 + i * 16 + ((lane >> 4) << 2) + r;
        const int col = wc * 32 + j * 16 + (lane & 15);
        lw[row * 68 + col] = acc[i][j][r];
      }
  __syncthreads();
  #pragma unroll
  for (int p = 0; p < 4; ++p){
    const int row = p * 32 + (tid >> 3);
    const int col8 = (tid & 7) * 8;
    const float4 v0 = *(const float4*)&lw[row * 68 + col8];
    const float4 v1 = *(const float4*)&lw[row * 68 + col8 + 4];
    bf16x8 o;
    o[0] = (__bf16)v0.x; o[1] = (__bf16)v0.y; o[2] = (__bf16)v0.z; o[3] = (__bf16)v0.w;
    o[4] = (__bf16)v1.x; o[5] = (__bf16)v1.y; o[6] = (__bf16)v1.z; o[7] = (__bf16)v1.w;
    *(bf16x8*)(C + (size_t)(bm + row) * N + bn + col8) = o;
  }
}

// ---------------- SpMM (CSR, wave per row, 16B gathers, multi-edge MLP) ----------------

// D=256: lanes split in 2 halves; half h handles edges idx=2j+h; each lane owns 8 channels.
__global__ __launch_bounds__(256)
void spmm_bias_relu_b16(const int2* __restrict__ ecv, const int* __restrict__ start,
                        const __bf16* __restrict__ H, const float* __restrict__ bias,
                        __bf16* __restrict__ out){
  const int w = (blockIdx.x * 256 + threadIdx.x) >> 6;
  const int lane = threadIdx.x & 63;
  const int half = lane >> 5, sl = lane & 31;
  if (w >= NN) return;
  const int s = start[w], e = start[w + 1];
  float a[8];
  #pragma unroll
  for (int k = 0; k < 8; ++k) a[k] = 0.f;
  for (int base = s; base < e; base += 64){
    int2 cv = make_int2(0, 0);
    if (base + lane < e) cv = ecv[base + lane];
    const int m = min(64, e - base);
    for (int j = 0; 2 * j < m; ++j){
      const int idx = 2 * j + half;
      int col = __shfl(cv.x, idx);
      float v = __int_as_float(__shfl(cv.y, idx));
      if (idx >= m){ col = 0; v = 0.f; }
      const bf16x8 h = *(const bf16x8*)(H + (size_t)col * 256 + sl * 8);
      #pragma unroll
      for (int k = 0; k < 8; ++k) a[k] = fmaf(v, (float)h[k], a[k]);
    }
  }
  #pragma unroll
  for (int k = 0; k < 8; ++k) a[k] += __shfl_xor(a[k], 32);
  const float4 b0 = *(const float4*)(bias + sl * 8);
  const float4 b1 = *(const float4*)(bias + sl * 8 + 4);
  bf16x8 o;
  o[0] = (__bf16)fmaxf(a[0] + b0.x, 0.f);
  o[1] = (__bf16)fmaxf(a[1] + b0.y, 0.f);
  o[2] = (__bf16)fmaxf(a[2] + b0.z, 0.f);
  o[3] = (__bf16)fmaxf(a[3] + b0.w, 0.f);
  o[4] = (__bf16)fmaxf(a[4] + b1.x, 0.f);
  o[5] = (__bf16)fmaxf(a[5] + b1.y, 0.f);
  o[6] = (__bf16)fmaxf(a[6] + b1.z, 0.f);
  o[7] = (__bf16)fmaxf(a[7] + b1.w, 0.f);
  if (half == 0) *(bf16x8*)(out + (size_t)w * 256 + sl * 8) = o;
}

// D=128: 4 quarters; quarter q handles edges idx=4j+q; each lane owns 8 channels.
__global__ __launch_bounds__(256)
void spmm_bias_norm_b16(const int2* __restrict__ ecv, const int* __restrict__ start,
                        const __bf16* __restrict__ H, const float* __restrict__ bias,
                        float* __restrict__ out){
  const int w = (blockIdx.x * 256 + threadIdx.x) >> 6;
  const int lane = threadIdx.x & 63;
  const int quar = lane >> 4, sl = lane & 15;
  if (w >= NN) return;
  const int s = start[w], e = start[w + 1];
  float a[8];
  #pragma unroll
  for (int k = 0; k < 8; ++k) a[k] = 0.f;
  for (int base = s; base < e; base += 64){
    int2 cv = make_int2(0, 0);
    if (base + lane < e) cv = ecv[base + lane];
    const int m = min(64, e - base);
    for (int j = 0; 4 * j < m; ++j){
      const int idx = 4 * j + quar;
      int col = __shfl(cv.x, idx);
      float v = __int_as_float(__shfl(cv.y, idx));
      if (idx >= m){ col = 0; v = 0.f; }
      const bf16x8 h = *(const bf16x8*)(H + (size_t)col * 128 + sl * 8);
      #pragma unroll
      for (int k = 0; k < 8; ++k) a[k] = fmaf(v, (float)h[k], a[k]);
    }
  }
  #pragma unroll
  for (int k = 0; k < 8; ++k){
    a[k] += __shfl_xor(a[k], 32);
    a[k] += __shfl_xor(a[k], 16);
  }
  const float4 b0 = *(const float4*)(bias + sl * 8);
  const float4 b1 = *(const float4*)(bias + sl * 8 + 4);
  float f[8];
  f[0] = a[0] + b0.x; f[1] = a[1] + b0.y; f[2] = a[2] + b0.z; f[3] = a[3] + b0.w;
  f[4] = a[4] + b1.x; f[5] = a[5] + b1.y; f[6] = a[6] + b1.z; f[7] = a[7] + b1.w;
  float ss = 0.f;
  #pragma unroll
  for (int k = 0; k < 8; ++k) ss = fmaf(f[k], f[k], ss);
  #pragma unroll
  for (int m2 = 1; m2 < 16; m2 <<= 1) ss += __shfl_xor(ss, m2);
  const float inv = 1.f / fmaxf(sqrtf(ss), 1e-12f);
  if (quar == 0){
    float4 o0 = make_float4(f[0] * inv, f[1] * inv, f[2] * inv, f[3] * inv);
    float4 o1 = make_float4(f[4] * inv, f[5] * inv, f[6] * inv, f[7] * inv);
    *(float4*)(out + (size_t)w * 128 + sl * 8) = o0;
    *(float4*)(out + (size_t)w * 128 + sl * 8 + 4) = o1;
  }
}

// ---------------- launch ----------------
// ws layout (bytes):
//  xb  @ 0          [50048][320] bf16 = 32,030,720
//  W1b @ 32030720   [256][320]  bf16 =    163,840
//  W2b @ 32194560   [128][256]  bf16 =     65,536
//  h1  @ 32260096   [50048][256] bf16 = 25,624,576
//  h2  @ 57884672   [50048][256] bf16 = 25,624,576
//  h3  @ 83509248   [50048][128] bf16 = 12,812,288
//  ecv @ 96321536   800000 int2       =  6,400,000
//  rs  @ 102721536  50001 int         =    200,016
//  part@ 102921552  ~200 int (pad)
//  cur @ 102922368  50000 int         =    200,000   total ~103.1 MB

extern "C" void kernel_launch(void* const* d_in, const int* in_sizes, int n_in,
                              void* d_out, int out_size, void* d_ws, size_t ws_size,
                              hipStream_t stream){
  const float* x    = (const float*)d_in[0];
  const int*   erow = (const int*)d_in[1];
  const int*   ecol = (const int*)d_in[2];
  const float* evalv= (const float*)d_in[3];
  const float* W1   = (const float*)d_in[4];
  const float* b1   = (const float*)d_in[5];
  const float* W2   = (const float*)d_in[6];
  const float* b2   = (const float*)d_in[7];
  float* out = (float*)d_out;

  char* ws = (char*)d_ws;
  __bf16* xb  = (__bf16*)(ws);
  __bf16* W1b = (__bf16*)(ws + 32030720);
  __bf16* W2b = (__bf16*)(ws + 32194560);
  __bf16* h1  = (__bf16*)(ws + 32260096);
  __bf16* h2  = (__bf16*)(ws + 57884672);
  __bf16* h3  = (__bf16*)(ws + 83509248);
  int2*   ecv = (int2*)(ws + 96321536);
  int*    rs  = (int*)(ws + 102721536);
  int*    part= (int*)(ws + 102921552);
  int*    cur = (int*)(ws + 102922368);

  // CSR build
  k_zero_i32<<<196, 256, 0, stream>>>(cur, NN);
  k_hist<<<3125, 256, 0, stream>>>(erow, cur);
  k_scan1<<<196, 256, 0, stream>>>(cur, rs, part, NN);
  k_scan2<<<1, 256, 0, stream>>>(part, 196);
  k_scan3<<<196, 256, 0, stream>>>(rs, part, NN);
  k_zero_i32<<<196, 256, 0, stream>>>(cur, NN);
  k_scatter<<<3125, 256, 0, stream>>>(erow, ecol, evalv, rs, cur, ecv);

  // conversions
  conv_bf16<<<15640, 256, 0, stream>>>(x, xb, NN, 300, 320);    // covers 50048 rows
  conv_bf16<<<80, 256, 0, stream>>>(W1, W1b, 256, 300, 320);
  conv_bf16<<<32, 256, 0, stream>>>(W2, W2b, 128, 256, 256);

  // layer 1: h1 = bf16(xb @ W1b^T); h2 = bf16(relu(A*h1 + b1))
  gemm_bf16<5><<<dim3(4, 391), 256, 0, stream>>>(xb, W1b, h1, 320, 256);
  spmm_bias_relu_b16<<<12500, 256, 0, stream>>>(ecv, rs, h1, b1, h2);
  k_zero_bf16<<<12, 256, 0, stream>>>(h2 + (size_t)NN * 256, 3072);   // pad rows

  // layer 2: h3 = bf16(h2 @ W2b^T); out = l2norm(A*h3 + b2)
  gemm_bf16<4><<<dim3(2, 391), 256, 0, stream>>>(h2, W2b, h3, 256, 128);
  spmm_bias_norm_b16<<<12500, 256, 0, stream>>>(ecv, rs, h3, b2, out);
}

// Round 5
// 210.837 us; speedup vs baseline: 2.4509x; 1.1721x over previous
//
#include <hip/hip_runtime.h>
#include <math.h>

#define NN 50000
#define NE 800000
#define ESLICE 200192   // 782 blocks * 256 threads; 4 slices cover NE

typedef __bf16 bf16x8 __attribute__((ext_vector_type(8)));
typedef __bf16 bf16x4 __attribute__((ext_vector_type(4)));
typedef float f32x4 __attribute__((ext_vector_type(4)));

__device__ __forceinline__ void gload16(const void* g, void* l){
  __builtin_amdgcn_global_load_lds((const __attribute__((address_space(1))) void*)g,
                                   (__attribute__((address_space(3))) void*)l, 16, 0, 0);
}

// ---------------- CSR build ----------------

__global__ void k_zero_i32(int* __restrict__ p, int n){
  int i = blockIdx.x * blockDim.x + threadIdx.x;
  if (i < n) p[i] = 0;
}

// rank+hist in one pass: pos[e] = running count of row; cnt ends as histogram.
// 4 edges per thread in independent slices -> 4 atomic round-trips in flight.
__global__ __launch_bounds__(256)
void k_rank(const int* __restrict__ erow, int* __restrict__ cnt, int* __restrict__ pos){
  const int t = blockIdx.x * 256 + threadIdx.x;
  #pragma unroll
  for (int k = 0; k < 4; ++k){
    const int e = t + k * ESLICE;
    if (e < NE){
      const int r = erow[e];
      pos[e] = atomicAdd(&cnt[r], 1);
    }
  }
}

__global__ __launch_bounds__(256)
void k_scan1(const int* __restrict__ cnt, int* __restrict__ rs, int* __restrict__ part, int n){
  const int t = threadIdx.x, b = blockIdx.x;
  const int i = b * 256 + t;
  int v = (i < n) ? cnt[i] : 0;
  const int lane = t & 63, w = t >> 6;
  int s = v;
  #pragma unroll
  for (int d = 1; d < 64; d <<= 1){ int u = __shfl_up(s, d); if (lane >= d) s += u; }
  __shared__ int wsum[4];
  if (lane == 63) wsum[w] = s;
  __syncthreads();
  int add = 0;
  #pragma unroll
  for (int k = 0; k < 4; ++k) if (k < w) add += wsum[k];
  s += add;
  if (i < n) rs[i + 1] = s;
  if (t == 255) part[b] = s;
}

__global__ __launch_bounds__(256)
void k_scan2(int* __restrict__ part, int nb){
  const int t = threadIdx.x;
  int v = (t < nb) ? part[t] : 0;
  const int lane = t & 63, w = t >> 6;
  int s = v;
  #pragma unroll
  for (int d = 1; d < 64; d <<= 1){ int u = __shfl_up(s, d); if (lane >= d) s += u; }
  __shared__ int wsum[4];
  if (lane == 63) wsum[w] = s;
  __syncthreads();
  int add = 0;
  #pragma unroll
  for (int k = 0; k < 4; ++k) if (k < w) add += wsum[k];
  s += add;
  if (t < nb) part[t] = s - v;
}

__global__ __launch_bounds__(256)
void k_scan3(int* __restrict__ rs, const int* __restrict__ part, int n){
  const int i = blockIdx.x * 256 + threadIdx.x;
  if (i < n) rs[i + 1] += part[blockIdx.x];
  if (i == 0) rs[0] = 0;
}

// atomic-free scatter: all loads independent, 4 edges per thread.
__global__ __launch_bounds__(256)
void k_scatter2(const int* __restrict__ erow, const int* __restrict__ ecol,
                const float* __restrict__ evalv, const int* __restrict__ rs,
                const int* __restrict__ pos, int2* __restrict__ out){
  const int t = blockIdx.x * 256 + threadIdx.x;
  #pragma unroll
  for (int k = 0; k < 4; ++k){
    const int e = t + k * ESLICE;
    if (e < NE){
      const int r = erow[e];
      const int p = rs[r] + pos[e];
      out[p] = make_int2(ecol[e], __float_as_int(evalv[e]));
    }
  }
}

// ---------------- fp32 -> bf16 conversion ----------------

__global__ __launch_bounds__(256)
void conv_bf16(const float* __restrict__ src, __bf16* __restrict__ dst,
               int M, int K, int Kp){
  const int q = blockIdx.x * 256 + threadIdx.x;
  const int perRow = Kp >> 2;
  const int r = q / perRow;
  const int k = (q - r * perRow) << 2;
  float4 v = make_float4(0.f, 0.f, 0.f, 0.f);
  if (r < M && k < K) v = *(const float4*)(src + (size_t)r * K + k);   // K % 4 == 0
  bf16x4 o;
  o[0] = (__bf16)v.x; o[1] = (__bf16)v.y; o[2] = (__bf16)v.z; o[3] = (__bf16)v.w;
  *(bf16x4*)(dst + (size_t)r * Kp + k) = o;
}

__global__ void k_zero_bf16(__bf16* __restrict__ p, int n4){
  int i = blockIdx.x * blockDim.x + threadIdx.x;
  if (i < n4){ bf16x4 z = {}; *(bf16x4*)(p + (size_t)i * 4) = z; }
}

// ---------------- bf16 MFMA GEMM, bf16 output ----------------

template<int KT>
__global__ __launch_bounds__(256)
void gemm_bf16(const __bf16* __restrict__ A, const __bf16* __restrict__ B,
               __bf16* __restrict__ C, int ld, int N){
  __shared__ char ldsbuf[49152];                 // 2 x (16KB A + 8KB B); epi reuses 34.8KB
  const int tid = threadIdx.x;
  const int lane = tid & 63;
  const int bn = blockIdx.x * 64;
  const int bm = blockIdx.y * 128;
  const int wr = (tid >> 7) & 1;
  const int wc = (tid >> 6) & 1;

  f32x4 acc[4][2];
  #pragma unroll
  for (int i = 0; i < 4; ++i)
    #pragma unroll
    for (int j = 0; j < 2; ++j) acc[i][j] = (f32x4){0.f, 0.f, 0.f, 0.f};

  auto stage = [&](int kt, int sel){
    char* lb = ldsbuf + sel * 24576;
    #pragma unroll
    for (int i = 0; i < 4; ++i){                 // A tile 16KB (128 rows x 128B)
      const int d = i * 4096 + tid * 16;
      const int row = d >> 7;
      const int colb = (d & 127) ^ ((row & 7) << 4);
      const __bf16* gp = A + (size_t)(bm + row) * ld + kt * 64 + (colb >> 1);
      gload16(gp, lb + i * 4096 + (tid & 192) * 16);
    }
    #pragma unroll
    for (int i = 0; i < 2; ++i){                 // B tile 8KB (64 rows x 128B)
      const int d = i * 4096 + tid * 16;
      const int row = d >> 7;
      const int colb = (d & 127) ^ ((row & 7) << 4);
      const __bf16* gp = B + (size_t)(bn + row) * ld + kt * 64 + (colb >> 1);
      gload16(gp, lb + 16384 + i * 4096 + (tid & 192) * 16);
    }
  };

  auto compute = [&](int sel){
    const char* lA = ldsbuf + sel * 24576;
    const char* lB = lA + 16384;
    #pragma unroll
    for (int c = 0; c < 2; ++c){
      bf16x8 av[4], bv[2];
      #pragma unroll
      for (int i = 0; i < 4; ++i){
        const int row = wr * 64 + i * 16 + (lane & 15);
        const int colb = (c * 64 + ((lane >> 4) << 4)) ^ ((row & 7) << 4);
        av[i] = *(const bf16x8*)(lA + row * 128 + colb);
      }
      #pragma unroll
      for (int j = 0; j < 2; ++j){
        const int row = wc * 32 + j * 16 + (lane & 15);
        const int colb = (c * 64 + ((lane >> 4) << 4)) ^ ((row & 7) << 4);
        bv[j] = *(const bf16x8*)(lB + row * 128 + colb);
      }
      #pragma unroll
      for (int i = 0; i < 4; ++i)
        #pragma unroll
        for (int j = 0; j < 2; ++j)
          acc[i][j] = __builtin_amdgcn_mfma_f32_16x16x32_bf16(av[i], bv[j], acc[i][j], 0, 0, 0);
    }
  };

  stage(0, 0);
  for (int kt = 0; kt < KT; ++kt){
    __syncthreads();
    if (kt + 1 < KT) stage(kt + 1, (kt + 1) & 1);
    compute(kt & 1);
  }

  // epilogue: acc -> LDS f32 [128][68] -> coalesced bf16x8 stores
  __syncthreads();
  float* lw = (float*)ldsbuf;
  #pragma unroll
  for (int i = 0; i < 4; ++i)
    #pragma unroll
    for (int j = 0; j < 2; ++j)
      #pragma unroll
      for (int r = 0; r < 4; ++r){
        const int row = wr * 64 + i * 16 + ((lane >> 4) << 2) + r;
        const int col = wc * 32 + j * 16 + (lane & 15);
        lw[row * 68 + col] = acc[i][j][r];
      }
  __syncthreads();
  #pragma unroll
  for (int p = 0; p < 4; ++p){
    const int row = p * 32 + (tid >> 3);
    const int col8 = (tid & 7) * 8;
    const float4 v0 = *(const float4*)&lw[row * 68 + col8];
    const float4 v1 = *(const float4*)&lw[row * 68 + col8 + 4];
    bf16x8 o;
    o[0] = (__bf16)v0.x; o[1] = (__bf16)v0.y; o[2] = (__bf16)v0.z; o[3] = (__bf16)v0.w;
    o[4] = (__bf16)v1.x; o[5] = (__bf16)v1.y; o[6] = (__bf16)v1.z; o[7] = (__bf16)v1.w;
    *(bf16x8*)(C + (size_t)(bm + row) * N + bn + col8) = o;
  }
}

// ---------------- SpMM (CSR, wave per row, 16B gathers, 4-8 edges in flight) ----------------

// D=256: half h handles edges idx%2==h; unrolled x2 -> 4 edges in flight.
__global__ __launch_bounds__(256)
void spmm_bias_relu_b16(const int2* __restrict__ ecv, const int* __restrict__ start,
                        const __bf16* __restrict__ H, const float* __restrict__ bias,
                        __bf16* __restrict__ out){
  const int w = (blockIdx.x * 256 + threadIdx.x) >> 6;
  const int lane = threadIdx.x & 63;
  const int half = lane >> 5, sl = lane & 31;
  if (w >= NN) return;
  const int s = start[w], e = start[w + 1];
  float a[8];
  #pragma unroll
  for (int k = 0; k < 8; ++k) a[k] = 0.f;
  for (int base = s; base < e; base += 64){
    int2 cv = make_int2(0, 0);
    if (base + lane < e) cv = ecv[base + lane];
    const int m = min(64, e - base);
    for (int j2 = 0; 4 * j2 < m; ++j2){
      const int idx0 = 4 * j2 + half;
      const int idx1 = idx0 + 2;
      int c0 = __shfl(cv.x, idx0);
      float v0 = __int_as_float(__shfl(cv.y, idx0));
      int c1 = __shfl(cv.x, idx1);
      float v1 = __int_as_float(__shfl(cv.y, idx1));
      if (idx0 >= m){ c0 = 0; v0 = 0.f; }
      if (idx1 >= m){ c1 = 0; v1 = 0.f; }
      const bf16x8 h0 = *(const bf16x8*)(H + (size_t)c0 * 256 + sl * 8);
      const bf16x8 h1 = *(const bf16x8*)(H + (size_t)c1 * 256 + sl * 8);
      #pragma unroll
      for (int k = 0; k < 8; ++k) a[k] = fmaf(v0, (float)h0[k], a[k]);
      #pragma unroll
      for (int k = 0; k < 8; ++k) a[k] = fmaf(v1, (float)h1[k], a[k]);
    }
  }
  #pragma unroll
  for (int k = 0; k < 8; ++k) a[k] += __shfl_xor(a[k], 32);
  const float4 b0 = *(const float4*)(bias + sl * 8);
  const float4 b1 = *(const float4*)(bias + sl * 8 + 4);
  bf16x8 o;
  o[0] = (__bf16)fmaxf(a[0] + b0.x, 0.f);
  o[1] = (__bf16)fmaxf(a[1] + b0.y, 0.f);
  o[2] = (__bf16)fmaxf(a[2] + b0.z, 0.f);
  o[3] = (__bf16)fmaxf(a[3] + b0.w, 0.f);
  o[4] = (__bf16)fmaxf(a[4] + b1.x, 0.f);
  o[5] = (__bf16)fmaxf(a[5] + b1.y, 0.f);
  o[6] = (__bf16)fmaxf(a[6] + b1.z, 0.f);
  o[7] = (__bf16)fmaxf(a[7] + b1.w, 0.f);
  if (half == 0) *(bf16x8*)(out + (size_t)w * 256 + sl * 8) = o;
}

// D=128: quarter q handles edges idx%4==q; unrolled x2 -> 8 edges in flight.
__global__ __launch_bounds__(256)
void spmm_bias_norm_b16(const int2* __restrict__ ecv, const int* __restrict__ start,
                        const __bf16* __restrict__ H, const float* __restrict__ bias,
                        float* __restrict__ out){
  const int w = (blockIdx.x * 256 + threadIdx.x) >> 6;
  const int lane = threadIdx.x & 63;
  const int quar = lane >> 4, sl = lane & 15;
  if (w >= NN) return;
  const int s = start[w], e = start[w + 1];
  float a[8];
  #pragma unroll
  for (int k = 0; k < 8; ++k) a[k] = 0.f;
  for (int base = s; base < e; base += 64){
    int2 cv = make_int2(0, 0);
    if (base + lane < e) cv = ecv[base + lane];
    const int m = min(64, e - base);
    for (int j2 = 0; 8 * j2 < m; ++j2){
      const int idx0 = 8 * j2 + quar;
      const int idx1 = idx0 + 4;
      int c0 = __shfl(cv.x, idx0);
      float v0 = __int_as_float(__shfl(cv.y, idx0));
      int c1 = __shfl(cv.x, idx1);
      float v1 = __int_as_float(__shfl(cv.y, idx1));
      if (idx0 >= m){ c0 = 0; v0 = 0.f; }
      if (idx1 >= m){ c1 = 0; v1 = 0.f; }
      const bf16x8 h0 = *(const bf16x8*)(H + (size_t)c0 * 128 + sl * 8);
      const bf16x8 h1 = *(const bf16x8*)(H + (size_t)c1 * 128 + sl * 8);
      #pragma unroll
      for (int k = 0; k < 8; ++k) a[k] = fmaf(v0, (float)h0[k], a[k]);
      #pragma unroll
      for (int k = 0; k < 8; ++k) a[k] = fmaf(v1, (float)h1[k], a[k]);
    }
  }
  #pragma unroll
  for (int k = 0; k < 8; ++k){
    a[k] += __shfl_xor(a[k], 32);
    a[k] += __shfl_xor(a[k], 16);
  }
  const float4 b0 = *(const float4*)(bias + sl * 8);
  const float4 b1 = *(const float4*)(bias + sl * 8 + 4);
  float f[8];
  f[0] = a[0] + b0.x; f[1] = a[1] + b0.y; f[2] = a[2] + b0.z; f[3] = a[3] + b0.w;
  f[4] = a[4] + b1.x; f[5] = a[5] + b1.y; f[6] = a[6] + b1.z; f[7] = a[7] + b1.w;
  float ss = 0.f;
  #pragma unroll
  for (int k = 0; k < 8; ++k) ss = fmaf(f[k], f[k], ss);
  #pragma unroll
  for (int m2 = 1; m2 < 16; m2 <<= 1) ss += __shfl_xor(ss, m2);
  const float inv = 1.f / fmaxf(sqrtf(ss), 1e-12f);
  if (quar == 0){
    float4 o0 = make_float4(f[0] * inv, f[1] * inv, f[2] * inv, f[3] * inv);
    float4 o1 = make_float4(f[4] * inv, f[5] * inv, f[6] * inv, f[7] * inv);
    *(float4*)(out + (size_t)w * 128 + sl * 8) = o0;
    *(float4*)(out + (size_t)w * 128 + sl * 8 + 4) = o1;
  }
}

// ---------------- launch ----------------
// ws layout (bytes):
//  xb  @ 0          [50048][320] bf16 = 32,030,720
//  W1b @ 32030720   [256][320]  bf16 =    163,840
//  W2b @ 32194560   [128][256]  bf16 =     65,536
//  h1  @ 32260096   [50048][256] bf16 = 25,624,576   (pos[800000] int aliases its head
//                                                     during CSR build; h1 written later)
//  h2  @ 57884672   [50048][256] bf16 = 25,624,576
//  h3  @ 83509248   [50048][128] bf16 = 12,812,288
//  ecv @ 96321536   800000 int2       =  6,400,000
//  rs  @ 102721536  50001 int         =    200,016
//  part@ 102921552  ~200 int (pad)
//  cur @ 102922368  50000 int         =    200,000   total ~103.1 MB

extern "C" void kernel_launch(void* const* d_in, const int* in_sizes, int n_in,
                              void* d_out, int out_size, void* d_ws, size_t ws_size,
                              hipStream_t stream){
  const float* x    = (const float*)d_in[0];
  const int*   erow = (const int*)d_in[1];
  const int*   ecol = (const int*)d_in[2];
  const float* evalv= (const float*)d_in[3];
  const float* W1   = (const float*)d_in[4];
  const float* b1   = (const float*)d_in[5];
  const float* W2   = (const float*)d_in[6];
  const float* b2   = (const float*)d_in[7];
  float* out = (float*)d_out;

  char* ws = (char*)d_ws;
  __bf16* xb  = (__bf16*)(ws);
  __bf16* W1b = (__bf16*)(ws + 32030720);
  __bf16* W2b = (__bf16*)(ws + 32194560);
  __bf16* h1  = (__bf16*)(ws + 32260096);
  __bf16* h2  = (__bf16*)(ws + 57884672);
  __bf16* h3  = (__bf16*)(ws + 83509248);
  int2*   ecv = (int2*)(ws + 96321536);
  int*    rs  = (int*)(ws + 102721536);
  int*    part= (int*)(ws + 102921552);
  int*    cur = (int*)(ws + 102922368);
  int*    pos = (int*)(ws + 32260096);     // aliases h1 head (dead until gemm1)

  // CSR build: rank(+hist) -> scan -> atomic-free scatter
  k_zero_i32<<<196, 256, 0, stream>>>(cur, NN);
  k_rank<<<782, 256, 0, stream>>>(erow, cur, pos);
  k_scan1<<<196, 256, 0, stream>>>(cur, rs, part, NN);
  k_scan2<<<1, 256, 0, stream>>>(part, 196);
  k_scan3<<<196, 256, 0, stream>>>(rs, part, NN);
  k_scatter2<<<782, 256, 0, stream>>>(erow, ecol, evalv, rs, pos, ecv);

  // conversions
  conv_bf16<<<15640, 256, 0, stream>>>(x, xb, NN, 300, 320);    // covers 50048 rows
  conv_bf16<<<80, 256, 0, stream>>>(W1, W1b, 256, 300, 320);
  conv_bf16<<<32, 256, 0, stream>>>(W2, W2b, 128, 256, 256);

  // layer 1: h1 = bf16(xb @ W1b^T); h2 = bf16(relu(A*h1 + b1))
  gemm_bf16<5><<<dim3(4, 391), 256, 0, stream>>>(xb, W1b, h1, 320, 256);
  spmm_bias_relu_b16<<<12500, 256, 0, stream>>>(ecv, rs, h1, b1, h2);
  k_zero_bf16<<<12, 256, 0, stream>>>(h2 + (size_t)NN * 256, 3072);   // pad rows

  // layer 2: h3 = bf16(h2 @ W2b^T); out = l2norm(A*h3 + b2)
  gemm_bf16<4><<<dim3(2, 391), 256, 0, stream>>>(h2, W2b, h3, 256, 128);
  spmm_bias_norm_b16<<<12500, 256, 0, stream>>>(ecv, rs, h3, b2, out);
}

// Round 6
// 202.273 us; speedup vs baseline: 2.5546x; 1.0423x over previous
//
#include <hip/hip_runtime.h>
#include <math.h>

#define NN 50000
#define NE 800000
#define ESLICE 200192   // 782 blocks * 256 threads; 4 slices cover NE

typedef __bf16 bf16x8 __attribute__((ext_vector_type(8)));
typedef __bf16 bf16x4 __attribute__((ext_vector_type(4)));
typedef float f32x4 __attribute__((ext_vector_type(4)));

__device__ __forceinline__ void gload16(const void* g, void* l){
  __builtin_amdgcn_global_load_lds((const __attribute__((address_space(1))) void*)g,
                                   (__attribute__((address_space(3))) void*)l, 16, 0, 0);
}

// ---------------- CSR build ----------------

__global__ void k_zero_i32(int* __restrict__ p, int n){
  int i = blockIdx.x * blockDim.x + threadIdx.x;
  if (i < n) p[i] = 0;
}

__global__ __launch_bounds__(256)
void k_rank(const int* __restrict__ erow, int* __restrict__ cnt, int* __restrict__ pos){
  const int t = blockIdx.x * 256 + threadIdx.x;
  #pragma unroll
  for (int k = 0; k < 4; ++k){
    const int e = t + k * ESLICE;
    if (e < NE){
      const int r = erow[e];
      pos[e] = atomicAdd(&cnt[r], 1);
    }
  }
}

__global__ __launch_bounds__(256)
void k_scan1(const int* __restrict__ cnt, int* __restrict__ rs, int* __restrict__ part, int n){
  const int t = threadIdx.x, b = blockIdx.x;
  const int i = b * 256 + t;
  int v = (i < n) ? cnt[i] : 0;
  const int lane = t & 63, w = t >> 6;
  int s = v;
  #pragma unroll
  for (int d = 1; d < 64; d <<= 1){ int u = __shfl_up(s, d); if (lane >= d) s += u; }
  __shared__ int wsum[4];
  if (lane == 63) wsum[w] = s;
  __syncthreads();
  int add = 0;
  #pragma unroll
  for (int k = 0; k < 4; ++k) if (k < w) add += wsum[k];
  s += add;
  if (i < n) rs[i + 1] = s;
  if (t == 255) part[b] = s;
}

__global__ __launch_bounds__(256)
void k_scan2(int* __restrict__ part, int nb){
  const int t = threadIdx.x;
  int v = (t < nb) ? part[t] : 0;
  const int lane = t & 63, w = t >> 6;
  int s = v;
  #pragma unroll
  for (int d = 1; d < 64; d <<= 1){ int u = __shfl_up(s, d); if (lane >= d) s += u; }
  __shared__ int wsum[4];
  if (lane == 63) wsum[w] = s;
  __syncthreads();
  int add = 0;
  #pragma unroll
  for (int k = 0; k < 4; ++k) if (k < w) add += wsum[k];
  s += add;
  if (t < nb) part[t] = s - v;
}

__global__ __launch_bounds__(256)
void k_scan3(int* __restrict__ rs, const int* __restrict__ part, int n){
  const int i = blockIdx.x * 256 + threadIdx.x;
  if (i < n) rs[i + 1] += part[blockIdx.x];
  if (i == 0) rs[0] = 0;
}

__global__ __launch_bounds__(256)
void k_scatter2(const int* __restrict__ erow, const int* __restrict__ ecol,
                const float* __restrict__ evalv, const int* __restrict__ rs,
                const int* __restrict__ pos, int2* __restrict__ out){
  const int t = blockIdx.x * 256 + threadIdx.x;
  #pragma unroll
  for (int k = 0; k < 4; ++k){
    const int e = t + k * ESLICE;
    if (e < NE){
      const int r = erow[e];
      const int p = rs[r] + pos[e];
      out[p] = make_int2(ecol[e], __float_as_int(evalv[e]));
    }
  }
}

// ---------------- fp32 -> bf16 conversion ----------------

__global__ __launch_bounds__(256)
void conv_bf16(const float* __restrict__ src, __bf16* __restrict__ dst,
               int M, int K, int Kp){
  const int q = blockIdx.x * 256 + threadIdx.x;
  const int perRow = Kp >> 2;
  const int r = q / perRow;
  const int k = (q - r * perRow) << 2;
  float4 v = make_float4(0.f, 0.f, 0.f, 0.f);
  if (r < M && k < K) v = *(const float4*)(src + (size_t)r * K + k);   // K % 4 == 0
  bf16x4 o;
  o[0] = (__bf16)v.x; o[1] = (__bf16)v.y; o[2] = (__bf16)v.z; o[3] = (__bf16)v.w;
  *(bf16x4*)(dst + (size_t)r * Kp + k) = o;
}

__global__ void k_zero_bf16(__bf16* __restrict__ p, int n4){
  int i = blockIdx.x * blockDim.x + threadIdx.x;
  if (i < n4){ bf16x4 z = {}; *(bf16x4*)(p + (size_t)i * 4) = z; }
}

// ---------------- bf16 MFMA GEMM, 128x128 tile, bf16 output ----------------
// C[Mpad][N] bf16 = A[Mpad][ld] * B[N][ld]^T. BM=BN=128, BK=64, 4 waves 2x2
// (wave tile 64x64), mfma 16x16x32, LDS linear dest + XOR-swizzled global src,
// bf16 LDS-transposed epilogue. Requires N % 128 == 0, Mpad % 128 == 0.

template<int KT>
__global__ __launch_bounds__(256)
void gemm_bf16(const __bf16* __restrict__ A, const __bf16* __restrict__ B,
               __bf16* __restrict__ C, int ld, int N){
  __shared__ char ldsbuf[65536];                 // 2 x (16KB A + 16KB B)
  const int tid = threadIdx.x;
  const int lane = tid & 63;
  const int bn = blockIdx.x * 128;
  const int bm = blockIdx.y * 128;
  const int wr = (tid >> 7) & 1;
  const int wc = (tid >> 6) & 1;

  f32x4 acc[4][4];
  #pragma unroll
  for (int i = 0; i < 4; ++i)
    #pragma unroll
    for (int j = 0; j < 4; ++j) acc[i][j] = (f32x4){0.f, 0.f, 0.f, 0.f};

  auto stage = [&](int kt, int sel){
    char* lb = ldsbuf + sel * 32768;
    #pragma unroll
    for (int i = 0; i < 4; ++i){                 // A tile 16KB (128 rows x 128B)
      const int d = i * 4096 + tid * 16;
      const int row = d >> 7;
      const int colb = (d & 127) ^ ((row & 7) << 4);
      const __bf16* gp = A + (size_t)(bm + row) * ld + kt * 64 + (colb >> 1);
      gload16(gp, lb + i * 4096 + (tid & 192) * 16);
    }
    #pragma unroll
    for (int i = 0; i < 4; ++i){                 // B tile 16KB (128 rows x 128B)
      const int d = i * 4096 + tid * 16;
      const int row = d >> 7;
      const int colb = (d & 127) ^ ((row & 7) << 4);
      const __bf16* gp = B + (size_t)(bn + row) * ld + kt * 64 + (colb >> 1);
      gload16(gp, lb + 16384 + i * 4096 + (tid & 192) * 16);
    }
  };

  auto compute = [&](int sel){
    const char* lA = ldsbuf + sel * 32768;
    const char* lB = lA + 16384;
    #pragma unroll
    for (int c = 0; c < 2; ++c){
      bf16x8 av[4], bv[4];
      #pragma unroll
      for (int i = 0; i < 4; ++i){
        const int row = wr * 64 + i * 16 + (lane & 15);
        const int colb = (c * 64 + ((lane >> 4) << 4)) ^ ((row & 7) << 4);
        av[i] = *(const bf16x8*)(lA + row * 128 + colb);
      }
      #pragma unroll
      for (int j = 0; j < 4; ++j){
        const int row = wc * 64 + j * 16 + (lane & 15);
        const int colb = (c * 64 + ((lane >> 4) << 4)) ^ ((row & 7) << 4);
        bv[j] = *(const bf16x8*)(lB + row * 128 + colb);
      }
      #pragma unroll
      for (int i = 0; i < 4; ++i)
        #pragma unroll
        for (int j = 0; j < 4; ++j)
          acc[i][j] = __builtin_amdgcn_mfma_f32_16x16x32_bf16(av[i], bv[j], acc[i][j], 0, 0, 0);
    }
  };

  stage(0, 0);
  for (int kt = 0; kt < KT; ++kt){
    __syncthreads();
    if (kt + 1 < KT) stage(kt + 1, (kt + 1) & 1);
    compute(kt & 1);
  }

  // epilogue: acc -> LDS bf16 [128][136] -> coalesced bf16x8 stores
  __syncthreads();
  __bf16* lw = (__bf16*)ldsbuf;
  #pragma unroll
  for (int i = 0; i < 4; ++i)
    #pragma unroll
    for (int j = 0; j < 4; ++j)
      #pragma unroll
      for (int r = 0; r < 4; ++r){
        const int row = wr * 64 + i * 16 + ((lane >> 4) << 2) + r;
        const int col = wc * 64 + j * 16 + (lane & 15);
        lw[row * 136 + col] = (__bf16)acc[i][j][r];
      }
  __syncthreads();
  #pragma unroll
  for (int p = 0; p < 8; ++p){
    const int idx = p * 256 + tid;               // 2048 chunks of 16B
    const int row = idx >> 4;
    const int c8 = (idx & 15) * 8;
    const bf16x8 o = *(const bf16x8*)&lw[row * 136 + c8];
    *(bf16x8*)(C + (size_t)(bm + row) * N + bn + c8) = o;
  }
}

// ---------------- SpMM (CSR, wave per row, 16-lane/edge quarters) ----------------

// D=256 processed in a 128-ch half per dispatch: quarter q handles edges idx%4==q,
// unroll x2 -> 8 edges in flight. H stride 256, out stride 256, channel base ch0.
__global__ __launch_bounds__(256)
void spmm_relu_half(const int2* __restrict__ ecv, const int* __restrict__ start,
                    const __bf16* __restrict__ H, const float* __restrict__ bias,
                    __bf16* __restrict__ out, int ch0){
  const int w = (blockIdx.x * 256 + threadIdx.x) >> 6;
  const int lane = threadIdx.x & 63;
  const int quar = lane >> 4, sl = lane & 15;
  if (w >= NN) return;
  const int s = start[w], e = start[w + 1];
  float a[8];
  #pragma unroll
  for (int k = 0; k < 8; ++k) a[k] = 0.f;
  for (int base = s; base < e; base += 64){
    int2 cv = make_int2(0, 0);
    if (base + lane < e) cv = ecv[base + lane];
    const int m = min(64, e - base);
    for (int j2 = 0; 8 * j2 < m; ++j2){
      const int idx0 = 8 * j2 + quar;
      const int idx1 = idx0 + 4;
      int c0 = __shfl(cv.x, idx0);
      float v0 = __int_as_float(__shfl(cv.y, idx0));
      int c1 = __shfl(cv.x, idx1);
      float v1 = __int_as_float(__shfl(cv.y, idx1));
      if (idx0 >= m){ c0 = 0; v0 = 0.f; }
      if (idx1 >= m){ c1 = 0; v1 = 0.f; }
      const bf16x8 h0 = *(const bf16x8*)(H + (size_t)c0 * 256 + ch0 + sl * 8);
      const bf16x8 h1 = *(const bf16x8*)(H + (size_t)c1 * 256 + ch0 + sl * 8);
      #pragma unroll
      for (int k = 0; k < 8; ++k) a[k] = fmaf(v0, (float)h0[k], a[k]);
      #pragma unroll
      for (int k = 0; k < 8; ++k) a[k] = fmaf(v1, (float)h1[k], a[k]);
    }
  }
  #pragma unroll
  for (int k = 0; k < 8; ++k){
    a[k] += __shfl_xor(a[k], 32);
    a[k] += __shfl_xor(a[k], 16);
  }
  const float4 b0 = *(const float4*)(bias + ch0 + sl * 8);
  const float4 b1 = *(const float4*)(bias + ch0 + sl * 8 + 4);
  bf16x8 o;
  o[0] = (__bf16)fmaxf(a[0] + b0.x, 0.f);
  o[1] = (__bf16)fmaxf(a[1] + b0.y, 0.f);
  o[2] = (__bf16)fmaxf(a[2] + b0.z, 0.f);
  o[3] = (__bf16)fmaxf(a[3] + b0.w, 0.f);
  o[4] = (__bf16)fmaxf(a[4] + b1.x, 0.f);
  o[5] = (__bf16)fmaxf(a[5] + b1.y, 0.f);
  o[6] = (__bf16)fmaxf(a[6] + b1.z, 0.f);
  o[7] = (__bf16)fmaxf(a[7] + b1.w, 0.f);
  if (quar == 0) *(bf16x8*)(out + (size_t)w * 256 + ch0 + sl * 8) = o;
}

// D=128: quarter q handles edges idx%4==q; unrolled x2 -> 8 edges in flight.
__global__ __launch_bounds__(256)
void spmm_bias_norm_b16(const int2* __restrict__ ecv, const int* __restrict__ start,
                        const __bf16* __restrict__ H, const float* __restrict__ bias,
                        float* __restrict__ out){
  const int w = (blockIdx.x * 256 + threadIdx.x) >> 6;
  const int lane = threadIdx.x & 63;
  const int quar = lane >> 4, sl = lane & 15;
  if (w >= NN) return;
  const int s = start[w], e = start[w + 1];
  float a[8];
  #pragma unroll
  for (int k = 0; k < 8; ++k) a[k] = 0.f;
  for (int base = s; base < e; base += 64){
    int2 cv = make_int2(0, 0);
    if (base + lane < e) cv = ecv[base + lane];
    const int m = min(64, e - base);
    for (int j2 = 0; 8 * j2 < m; ++j2){
      const int idx0 = 8 * j2 + quar;
      const int idx1 = idx0 + 4;
      int c0 = __shfl(cv.x, idx0);
      float v0 = __int_as_float(__shfl(cv.y, idx0));
      int c1 = __shfl(cv.x, idx1);
      float v1 = __int_as_float(__shfl(cv.y, idx1));
      if (idx0 >= m){ c0 = 0; v0 = 0.f; }
      if (idx1 >= m){ c1 = 0; v1 = 0.f; }
      const bf16x8 h0 = *(const bf16x8*)(H + (size_t)c0 * 128 + sl * 8);
      const bf16x8 h1 = *(const bf16x8*)(H + (size_t)c1 * 128 + sl * 8);
      #pragma unroll
      for (int k = 0; k < 8; ++k) a[k] = fmaf(v0, (float)h0[k], a[k]);
      #pragma unroll
      for (int k = 0; k < 8; ++k) a[k] = fmaf(v1, (float)h1[k], a[k]);
    }
  }
  #pragma unroll
  for (int k = 0; k < 8; ++k){
    a[k] += __shfl_xor(a[k], 32);
    a[k] += __shfl_xor(a[k], 16);
  }
  const float4 b0 = *(const float4*)(bias + sl * 8);
  const float4 b1 = *(const float4*)(bias + sl * 8 + 4);
  float f[8];
  f[0] = a[0] + b0.x; f[1] = a[1] + b0.y; f[2] = a[2] + b0.z; f[3] = a[3] + b0.w;
  f[4] = a[4] + b1.x; f[5] = a[5] + b1.y; f[6] = a[6] + b1.z; f[7] = a[7] + b1.w;
  float ss = 0.f;
  #pragma unroll
  for (int k = 0; k < 8; ++k) ss = fmaf(f[k], f[k], ss);
  #pragma unroll
  for (int m2 = 1; m2 < 16; m2 <<= 1) ss += __shfl_xor(ss, m2);
  const float inv = 1.f / fmaxf(sqrtf(ss), 1e-12f);
  if (quar == 0){
    float4 o0 = make_float4(f[0] * inv, f[1] * inv, f[2] * inv, f[3] * inv);
    float4 o1 = make_float4(f[4] * inv, f[5] * inv, f[6] * inv, f[7] * inv);
    *(float4*)(out + (size_t)w * 128 + sl * 8) = o0;
    *(float4*)(out + (size_t)w * 128 + sl * 8 + 4) = o1;
  }
}

// ---------------- launch ----------------
// ws layout (bytes):
//  xb  @ 0          [50048][320] bf16 = 32,030,720
//  W1b @ 32030720   [256][320]  bf16 =    163,840
//  W2b @ 32194560   [128][256]  bf16 =     65,536
//  h1  @ 32260096   [50048][256] bf16 = 25,624,576   (pos[800000] aliases head in CSR build)
//  h2  @ 57884672   [50048][256] bf16 = 25,624,576
//  h3  @ 83509248   [50048][128] bf16 = 12,812,288
//  ecv @ 96321536   800000 int2       =  6,400,000
//  rs  @ 102721536  50001 int         =    200,016
//  part@ 102921552  ~200 int (pad)
//  cur @ 102922368  50000 int         =    200,000   total ~103.1 MB

extern "C" void kernel_launch(void* const* d_in, const int* in_sizes, int n_in,
                              void* d_out, int out_size, void* d_ws, size_t ws_size,
                              hipStream_t stream){
  const float* x    = (const float*)d_in[0];
  const int*   erow = (const int*)d_in[1];
  const int*   ecol = (const int*)d_in[2];
  const float* evalv= (const float*)d_in[3];
  const float* W1   = (const float*)d_in[4];
  const float* b1   = (const float*)d_in[5];
  const float* W2   = (const float*)d_in[6];
  const float* b2   = (const float*)d_in[7];
  float* out = (float*)d_out;

  char* ws = (char*)d_ws;
  __bf16* xb  = (__bf16*)(ws);
  __bf16* W1b = (__bf16*)(ws + 32030720);
  __bf16* W2b = (__bf16*)(ws + 32194560);
  __bf16* h1  = (__bf16*)(ws + 32260096);
  __bf16* h2  = (__bf16*)(ws + 57884672);
  __bf16* h3  = (__bf16*)(ws + 83509248);
  int2*   ecv = (int2*)(ws + 96321536);
  int*    rs  = (int*)(ws + 102721536);
  int*    part= (int*)(ws + 102921552);
  int*    cur = (int*)(ws + 102922368);
  int*    pos = (int*)(ws + 32260096);     // aliases h1 head (dead until gemm1)

  // CSR build: rank(+hist) -> scan -> atomic-free scatter
  k_zero_i32<<<196, 256, 0, stream>>>(cur, NN);
  k_rank<<<782, 256, 0, stream>>>(erow, cur, pos);
  k_scan1<<<196, 256, 0, stream>>>(cur, rs, part, NN);
  k_scan2<<<1, 256, 0, stream>>>(part, 196);
  k_scan3<<<196, 256, 0, stream>>>(rs, part, NN);
  k_scatter2<<<782, 256, 0, stream>>>(erow, ecol, evalv, rs, pos, ecv);

  // conversions
  conv_bf16<<<15640, 256, 0, stream>>>(x, xb, NN, 300, 320);    // covers 50048 rows
  conv_bf16<<<80, 256, 0, stream>>>(W1, W1b, 256, 300, 320);
  conv_bf16<<<32, 256, 0, stream>>>(W2, W2b, 128, 256, 256);

  // layer 1: h1 = bf16(xb @ W1b^T); h2 = bf16(relu(A*h1 + b1)) in two 128-ch halves
  gemm_bf16<5><<<dim3(2, 391), 256, 0, stream>>>(xb, W1b, h1, 320, 256);
  spmm_relu_half<<<12500, 256, 0, stream>>>(ecv, rs, h1, b1, h2, 0);
  spmm_relu_half<<<12500, 256, 0, stream>>>(ecv, rs, h1, b1, h2, 128);
  k_zero_bf16<<<12, 256, 0, stream>>>(h2 + (size_t)NN * 256, 3072);   // pad rows

  // layer 2: h3 = bf16(h2 @ W2b^T); out = l2norm(A*h3 + b2)
  gemm_bf16<4><<<dim3(1, 391), 256, 0, stream>>>(h2, W2b, h3, 256, 128);
  spmm_bias_norm_b16<<<12500, 256, 0, stream>>>(ecv, rs, h3, b2, out);
}